// Round 9
// baseline (1092.655 us; speedup 1.0000x reference)
//
#include <hip/hip_runtime.h>
#include <hip/hip_bf16.h>

#define H 128
#define ND 4000
#define NPN 19000
#define NCN 1000
#define NLAYERS 2
#define NB 30000
#define E_DP 200000
#define E_PP 300000
#define E_CP 150000
#define NW 32
#define WSMAX 608

typedef __bf16 bf16_t;
typedef bf16_t bf16x8 __attribute__((ext_vector_type(8)));
typedef float f32x4 __attribute__((ext_vector_type(4)));
typedef unsigned short u16;

static __device__ __forceinline__ float wred_sum(float v) {
#pragma unroll
  for (int off = 32; off; off >>= 1) v += __shfl_xor(v, off);
  return v;
}
static __device__ __forceinline__ float bflo(unsigned u) { return __uint_as_float(u << 16); }
static __device__ __forceinline__ float bfhi(unsigned u) { return __uint_as_float(u & 0xffff0000u); }
static __device__ __forceinline__ unsigned packbf(float v0, float v1) {
  union { bf16_t b; unsigned short u; } a, b;
  a.b = (bf16_t)v0; b.b = (bf16_t)v1;
  return (unsigned)a.u | ((unsigned)b.u << 16);
}

// async global->LDS, 16B per lane
#define GLDS16(gp, lp) \
  __builtin_amdgcn_global_load_lds((__attribute__((address_space(1))) void*)(gp), \
                                   (__attribute__((address_space(3))) void*)(lp), 16, 0, 0)

// ================= MFMA GEMM core (fills acc; epilogue is per-kernel) =================
__device__ __forceinline__ void mfma_core(
    const bf16_t* __restrict__ A, const bf16_t* __restrict__ Bt,
    int M, int K, int ldb, int m0, int n0, f32x4 (&acc)[4][4])
{
  __shared__ char As[128 * 64];
  __shared__ char Bs[128 * 64];
  const int t = threadIdx.x;
  const int lane = t & 63;
#pragma unroll
  for (int mi = 0; mi < 4; ++mi)
#pragma unroll
    for (int ni = 0; ni < 4; ++ni) acc[mi][ni] = (f32x4){0.f, 0.f, 0.f, 0.f};

  const int wid = t >> 6;
  const int wr = wid >> 1, wc = wid & 1;
  const int sr = t >> 2;
  const int sc = t & 3;
  const int csrc = ((sc ^ ((sr >> 1) & 3)) << 4);
  int ra0 = m0 + sr;      if (ra0 >= M) ra0 = M - 1;
  int ra1 = m0 + 64 + sr; if (ra1 >= M) ra1 = M - 1;
  const char* gA0 = (const char*)A + (size_t)ra0 * K * 2 + csrc;
  const char* gA1 = (const char*)A + (size_t)ra1 * K * 2 + csrc;
  const char* gB0 = (const char*)Bt + (size_t)(n0 + sr) * ldb * 2 + csrc;
  const char* gB1 = (const char*)Bt + (size_t)(n0 + 64 + sr) * ldb * 2 + csrc;
  char* lA0 = As + t * 16;
  char* lA1 = As + 4096 + t * 16;
  char* lB0 = Bs + t * 16;
  char* lB1 = Bs + 4096 + t * 16;

  int aoff[4], boff[4];
#pragma unroll
  for (int mi = 0; mi < 4; ++mi) {
    int r = wr * 64 + mi * 16 + (lane & 15);
    aoff[mi] = r * 64 + ((((lane >> 4)) ^ ((r >> 1) & 3)) << 4);
  }
#pragma unroll
  for (int ni = 0; ni < 4; ++ni) {
    int r = wc * 64 + ni * 16 + (lane & 15);
    boff[ni] = r * 64 + ((((lane >> 4)) ^ ((r >> 1) & 3)) << 4);
  }

  for (int k0 = 0; k0 < K; k0 += 32) {
    const size_t kb = (size_t)k0 * 2;
    __syncthreads();
    GLDS16(gA0 + kb, lA0);
    GLDS16(gA1 + kb, lA1);
    GLDS16(gB0 + kb, lB0);
    GLDS16(gB1 + kb, lB1);
    __syncthreads();
    bf16x8 av[4], bv[4];
#pragma unroll
    for (int mi = 0; mi < 4; ++mi) av[mi] = *(const bf16x8*)(As + aoff[mi]);
#pragma unroll
    for (int ni = 0; ni < 4; ++ni) bv[ni] = *(const bf16x8*)(Bs + boff[ni]);
#pragma unroll
    for (int mi = 0; mi < 4; ++mi)
#pragma unroll
      for (int ni = 0; ni < 4; ++ni)
        acc[mi][ni] = __builtin_amdgcn_mfma_f32_16x16x32_bf16(av[mi], bv[ni], acc[mi][ni], 0, 0, 0);
  }
}

// --- GAT dst-side transform: C = relu(y @ Wt + biases), bf16 out, N=128 ---
struct GJob { const bf16_t* A; const bf16_t* Bt; bf16_t* C; int M; int K;
              const float *b1, *b2, *b3; };
struct Gemm3 { GJob j[3]; };
__global__ __launch_bounds__(256) void k_gemm_g3(Gemm3 g) {
  const GJob& jb = g.j[blockIdx.y];
  int m0 = blockIdx.x * 128;
  if (m0 >= jb.M) return;
  f32x4 acc[4][4];
  mfma_core(jb.A, jb.Bt, jb.M, jb.K, jb.K, m0, 0, acc);
  const int t = threadIdx.x, lane = t & 63, wid = t >> 6;
  const int wr = wid >> 1, wc = wid & 1;
  const int col0 = lane & 15, rsub = (lane >> 4) * 4;
#pragma unroll
  for (int mi = 0; mi < 4; ++mi) {
#pragma unroll
    for (int ni = 0; ni < 4; ++ni) {
      int c = wc * 64 + ni * 16 + col0;
      float bb = jb.b1[c];
      if (jb.b2) bb += jb.b2[c];
      if (jb.b3) bb += jb.b3[c];
#pragma unroll
      for (int rg = 0; rg < 4; ++rg) {
        int r = m0 + wr * 64 + mi * 16 + rsub + rg;
        if (r < jb.M) jb.C[(size_t)r * H + c] = (bf16_t)fmaxf(acc[mi][ni][rg] + bb, 0.f);
      }
    }
  }
}

// --- head slice GEMMs: P = (x @ W1slice) * rowscale + b1/3, bf16 out ---
struct PJob { const bf16_t* A; bf16_t* C; int M; const float* rs; };
struct GemmPS { PJob j[3]; const bf16_t* Bt; const float* b1t; };
__global__ __launch_bounds__(256) void k_gemm_ps(GemmPS g) {
  const PJob& jb = g.j[blockIdx.y];
  int mt = blockIdx.x / 6, nt = blockIdx.x - mt * 6;
  int m0 = mt * 128;
  if (m0 >= jb.M) return;
  int n0 = nt * 128;
  f32x4 acc[4][4];
  mfma_core(jb.A, g.Bt + blockIdx.y * 128, jb.M, 128, 384, m0, n0, acc);
  const int t = threadIdx.x, lane = t & 63, wid = t >> 6;
  const int wr = wid >> 1, wc = wid & 1;
  const int col0 = lane & 15, rsub = (lane >> 4) * 4;
#pragma unroll
  for (int mi = 0; mi < 4; ++mi) {
#pragma unroll
    for (int rg = 0; rg < 4; ++rg) {
      int r = m0 + wr * 64 + mi * 16 + rsub + rg;
      if (r < jb.M) {
        float sc = jb.rs[r];
#pragma unroll
        for (int ni = 0; ni < 4; ++ni) {
          int c = n0 + wc * 64 + ni * 16 + col0;
          jb.C[(size_t)r * 768 + c] = (bf16_t)(acc[mi][ni][rg] * sc + g.b1t[c]);
        }
      }
    }
  }
}

// --- fused head, BN=256 single pass ---
__global__ __launch_bounds__(256) void k_w2head(
    const bf16_t* __restrict__ Pa, const bf16_t* __restrict__ Pb, const bf16_t* __restrict__ Pc,
    const int* __restrict__ d1, const int* __restrict__ d2, const int* __restrict__ ce,
    const bf16_t* __restrict__ W2t, const float* __restrict__ b2,
    const float* __restrict__ W3, const float* __restrict__ b3,
    float* __restrict__ out, int cn)
{
  __shared__ char As[128 * 64];
  __shared__ char Bs[256 * 64];
  const int t = threadIdx.x;
  const int lane = t & 63;
  const int m0 = blockIdx.x * 128;
  if (m0 >= cn) return;
  f32x4 acc[4][8];
#pragma unroll
  for (int mi = 0; mi < 4; ++mi)
#pragma unroll
    for (int ni = 0; ni < 8; ++ni) acc[mi][ni] = (f32x4){0.f, 0.f, 0.f, 0.f};

  const int arow = t >> 1;
  const int ah = t & 1;
  int gr = m0 + arow; if (gr >= cn) gr = cn - 1;
  const bf16_t* pa = Pa + (size_t)d1[gr] * 768 + ah * 16;
  const bf16_t* pb = Pb + (size_t)d2[gr] * 768 + ah * 16;
  const bf16_t* pc = Pc + (size_t)ce[gr] * 768 + ah * 16;
  const int swz = (arow >> 1) & 3;
  char* la0 = As + arow * 64 + (((ah * 2)     ^ swz) << 4);
  char* la1 = As + arow * 64 + (((ah * 2 + 1) ^ swz) << 4);

  const int sr = t >> 2;
  const int sc = t & 3;
  const int csrc = ((sc ^ ((sr >> 1) & 3)) << 4);
  const char* gB = (const char*)W2t + (size_t)sr * 768 * 2 + csrc;
  const size_t qstep = (size_t)64 * 768 * 2;

  const int wid = t >> 6;
  const int wr = wid >> 1, wc = wid & 1;
  int aoff[4], boff[8];
#pragma unroll
  for (int mi = 0; mi < 4; ++mi) {
    int r = wr * 64 + mi * 16 + (lane & 15);
    aoff[mi] = r * 64 + ((((lane >> 4)) ^ ((r >> 1) & 3)) << 4);
  }
#pragma unroll
  for (int ni = 0; ni < 8; ++ni) {
    int r = wc * 128 + ni * 16 + (lane & 15);
    boff[ni] = r * 64 + ((((lane >> 4)) ^ ((r >> 1) & 3)) << 4);
  }

#define ACC8(U, o) { s[o+0] += bflo(U.x); s[o+1] += bfhi(U.x); s[o+2] += bflo(U.y); s[o+3] += bfhi(U.y); \
                     s[o+4] += bflo(U.z); s[o+5] += bfhi(U.z); s[o+6] += bflo(U.w); s[o+7] += bfhi(U.w); }
  for (int k0 = 0; k0 < 768; k0 += 32) {
    uint4 Ua0 = *(const uint4*)(pa + k0);
    uint4 Ua1 = *(const uint4*)(pa + k0 + 8);
    uint4 Ub0 = *(const uint4*)(pb + k0);
    uint4 Ub1 = *(const uint4*)(pb + k0 + 8);
    uint4 Uc0 = *(const uint4*)(pc + k0);
    uint4 Uc1 = *(const uint4*)(pc + k0 + 8);
    float s[16] = {0.f, 0.f, 0.f, 0.f, 0.f, 0.f, 0.f, 0.f,
                   0.f, 0.f, 0.f, 0.f, 0.f, 0.f, 0.f, 0.f};
    ACC8(Ua0, 0) ACC8(Ua1, 8)
    ACC8(Ub0, 0) ACC8(Ub1, 8)
    ACC8(Uc0, 0) ACC8(Uc1, 8)
    uint4 P0, P1;
    P0.x = packbf(fmaxf(s[0], 0.f),  fmaxf(s[1], 0.f));
    P0.y = packbf(fmaxf(s[2], 0.f),  fmaxf(s[3], 0.f));
    P0.z = packbf(fmaxf(s[4], 0.f),  fmaxf(s[5], 0.f));
    P0.w = packbf(fmaxf(s[6], 0.f),  fmaxf(s[7], 0.f));
    P1.x = packbf(fmaxf(s[8], 0.f),  fmaxf(s[9], 0.f));
    P1.y = packbf(fmaxf(s[10], 0.f), fmaxf(s[11], 0.f));
    P1.z = packbf(fmaxf(s[12], 0.f), fmaxf(s[13], 0.f));
    P1.w = packbf(fmaxf(s[14], 0.f), fmaxf(s[15], 0.f));
    const size_t kb = (size_t)k0 * 2;
    __syncthreads();
    GLDS16(gB + kb,             Bs + t * 16);
    GLDS16(gB + qstep + kb,     Bs + 4096 + t * 16);
    GLDS16(gB + 2 * qstep + kb, Bs + 8192 + t * 16);
    GLDS16(gB + 3 * qstep + kb, Bs + 12288 + t * 16);
    *(uint4*)la0 = P0;
    *(uint4*)la1 = P1;
    __syncthreads();
    bf16x8 av[4], bv[8];
#pragma unroll
    for (int mi = 0; mi < 4; ++mi) av[mi] = *(const bf16x8*)(As + aoff[mi]);
#pragma unroll
    for (int ni = 0; ni < 8; ++ni) bv[ni] = *(const bf16x8*)(Bs + boff[ni]);
#pragma unroll
    for (int mi = 0; mi < 4; ++mi)
#pragma unroll
      for (int ni = 0; ni < 8; ++ni)
        acc[mi][ni] = __builtin_amdgcn_mfma_f32_16x16x32_bf16(av[mi], bv[ni], acc[mi][ni], 0, 0, 0);
  }
#undef ACC8

  const int col0 = lane & 15, rsub = (lane >> 4) * 4;
  float w0[8], w1[8], bb[8];
#pragma unroll
  for (int ni = 0; ni < 8; ++ni) {
    int c = wc * 128 + ni * 16 + col0;
    w0[ni] = W3[2 * c]; w1[ni] = W3[2 * c + 1]; bb[ni] = b2[c];
  }
#pragma unroll
  for (int mi = 0; mi < 4; ++mi) {
#pragma unroll
    for (int rg = 0; rg < 4; ++rg) {
      int r = m0 + wr * 64 + mi * 16 + rsub + rg;
      float p0 = 0.f, p1 = 0.f;
#pragma unroll
      for (int ni = 0; ni < 8; ++ni) {
        float v = fmaxf(acc[mi][ni][rg] + bb[ni], 0.f);
        p0 = fmaf(v, w0[ni], p0);
        p1 = fmaf(v, w1[ni], p1);
      }
#pragma unroll
      for (int off = 1; off < 16; off <<= 1) {
        p0 += __shfl_xor(p0, off);
        p1 += __shfl_xor(p1, off);
      }
      if (col0 == 0 && r < cn) {
        if (wc == 0) { p0 += b3[0]; p1 += b3[1]; }
        atomicAdd(&out[(size_t)r * 2], p0);
        atomicAdd(&out[(size_t)r * 2 + 1], p1);
      }
    }
  }
}

// ================= conversions =================
__global__ __launch_bounds__(256) void k_conv_emb(
    const float* __restrict__ xd, const float* __restrict__ xp, const float* __restrict__ xc,
    bf16_t* __restrict__ od, bf16_t* __restrict__ op, bf16_t* __restrict__ oc)
{
  int i = blockIdx.x * 256 + threadIdx.x;
  const int SD = ND * H, SP = NPN * H, SC = NCN * H;
  if (i < SD) od[i] = (bf16_t)xd[i];
  else if (i < SD + SP) op[i - SD] = (bf16_t)xp[i - SD];
  else if (i < SD + SP + SC) oc[i - SD - SP] = (bf16_t)xc[i - SD - SP];
}

__global__ __launch_bounds__(256) void k_scale3(const float* __restrict__ b1, float* __restrict__ o) {
  int i = blockIdx.x * 256 + threadIdx.x;
  if (i < 768) o[i] = b1[i] * (1.f / 3.f);
}

// LDS-tiled transpose-convert: dst[n*Kfull+koff+k] = bf16(src[k*N+n])
struct TC { const float* src[12]; bf16_t* dst[12]; int Ksub[12]; int N[12]; int Kfull[12]; int koff[12]; };
__global__ __launch_bounds__(256) void k_tconv2(TC a) {
  int m = blockIdx.z;
  int Ks = a.Ksub[m], N = a.N[m];
  int tx = blockIdx.x * 32;
  int ty = blockIdx.y * 32;
  if (tx >= N || ty >= Ks) return;
  __shared__ float tile[32][33];
  int c = threadIdx.x & 31, rr = threadIdx.x >> 5;
#pragma unroll
  for (int kk = rr; kk < 32; kk += 8)
    if (ty + kk < Ks && tx + c < N) tile[kk][c] = a.src[m][(size_t)(ty + kk) * N + tx + c];
  __syncthreads();
  bf16_t* dst = a.dst[m];
  int Kf = a.Kfull[m], ko = a.koff[m];
#pragma unroll
  for (int nn = rr; nn < 32; nn += 8)
    if (tx + nn < N && ty + c < Ks)
      dst[(size_t)(tx + nn) * Kf + ko + ty + c] = (bf16_t)tile[c][nn];
}

// ---------------- wv = W @ a : both layers, 20 matvecs ----------------
struct Wd20 { const float* W[20]; const float* a[20]; float* o[20]; };
__global__ __launch_bounds__(128) void k_wd20(Wd20 g) {
  int m = blockIdx.x;
  int k = threadIdx.x;
  const float* Wp = g.W[m];
  const float* av = g.a[m];
  float s = 0.f;
#pragma unroll 4
  for (int j = 0; j < H; ++j) s = fmaf(Wp[k * H + j], av[j], s);
  g.o[m][k] = s;
}

// ---------------- fused node scores ----------------
struct Sc { const bf16_t* xd; const bf16_t* xp; const bf16_t* xc; const float* wv;
            float* ss[5]; float* sd[5]; };
__global__ __launch_bounds__(256) void k_scores(Sc S) {
  int row = blockIdx.x * 4 + (threadIdx.x >> 6);
  if (row >= ND + NPN + NCN) return;
  int lane = threadIdx.x & 63;
  const bf16_t* x;
  int idx, cls;
  if (row < ND) { x = S.xd; idx = row; cls = 0; }
  else if (row < ND + NPN) { x = S.xp; idx = row - ND; cls = 1; }
  else { x = S.xc; idx = row - ND - NPN; cls = 2; }
  unsigned u = *(const unsigned*)(x + (size_t)idx * H + lane * 2);
  float x0 = bflo(u), x1 = bfhi(u);
  const float* wv = S.wv;
#define DOT(vi, outp) { const float* v = wv + (vi) * H; \
    float s = x0 * v[2 * lane] + x1 * v[2 * lane + 1]; s = wred_sum(s); \
    if (!lane) (outp)[idx] = s; }
  if (cls == 0) {
    DOT(0, S.ss[0]); DOT(8, S.sd[3]);
  } else if (cls == 1) {
    DOT(1, S.ss[1]); DOT(3, S.ss[3]); DOT(4, S.ss[4]);
    DOT(5, S.sd[0]); DOT(6, S.sd[1]); DOT(7, S.sd[2]);
  } else {
    DOT(2, S.ss[2]); DOT(9, S.sd[4]);
  }
#undef DOT
}

// ---------------- CSR build: windowed (LDS counters, localized writes) ----------------
struct CsrW {
  const int* src[5]; const int* dst[5];
  int E[5]; int n[5]; int ws[5];
  int* cnt[5]; int* starts[5]; u16* csr[5];
};
// one block per (window, rel): scan dst[], count LDS-local, write cnt window contiguous
__global__ __launch_bounds__(256) void k_countw(CsrW a) {
  int rel = blockIdx.y;
  int ws = a.ws[rel], n = a.n[rel];
  int w0 = blockIdx.x * ws;
  if (w0 >= n) return;
  int wn = n - w0; if (wn > ws) wn = ws;
  __shared__ int lcnt[WSMAX];
  for (int i = threadIdx.x; i < wn; i += 256) lcnt[i] = 0;
  __syncthreads();
  const int* dst = a.dst[rel];
  int E = a.E[rel];
  for (int base = 0; base < E; base += 1024) {
#pragma unroll
    for (int u = 0; u < 4; ++u) {
      int e = base + u * 256 + threadIdx.x;
      if (e < E) {
        int d = dst[e] - w0;
        if ((unsigned)d < (unsigned)wn) atomicAdd(&lcnt[d], 1);
      }
    }
  }
  __syncthreads();
  int* cnt = a.cnt[rel];
  for (int i = threadIdx.x; i < wn; i += 256) cnt[w0 + i] = lcnt[i];
}
__global__ __launch_bounds__(1024) void k_scan5(CsrW a) {
  int rel = blockIdx.x;
  int n = a.n[rel];
  const int* cnt = a.cnt[rel];
  int* st = a.starts[rel];
  int t = threadIdx.x;
  int stripe = (n + 1023) / 1024;
  int lo = t * stripe;
  int hi = lo + stripe; if (hi > n) hi = n;
  int s = 0;
  for (int i = lo; i < hi; ++i) s += cnt[i];
  int lane = t & 63, wv = t >> 6;
  int x = s;
#pragma unroll
  for (int off = 1; off < 64; off <<= 1) {
    int y = __shfl_up(x, off);
    if (lane >= off) x += y;
  }
  __shared__ int ws[16];
  if (lane == 63) ws[wv] = x;
  __syncthreads();
  if (t == 0) {
    int run = 0;
#pragma unroll
    for (int i = 0; i < 16; ++i) { int v = ws[i]; ws[i] = run; run += v; }
  }
  __syncthreads();
  int run = ws[wv] + x - s;
  for (int i = lo; i < hi; ++i) { st[i] = run; run += cnt[i]; }
  if (t == 1023) st[n] = ws[15] + x;
}
// one block per (window, rel): scan src+dst, LDS cursors from starts, write csr window
__global__ __launch_bounds__(256) void k_fillw(CsrW a) {
  int rel = blockIdx.y;
  int ws = a.ws[rel], n = a.n[rel];
  int w0 = blockIdx.x * ws;
  if (w0 >= n) return;
  int wn = n - w0; if (wn > ws) wn = ws;
  __shared__ int lcur[WSMAX];
  const int* st = a.starts[rel];
  for (int i = threadIdx.x; i < wn; i += 256) lcur[i] = st[w0 + i];
  __syncthreads();
  const int* dst = a.dst[rel];
  const int* src = a.src[rel];
  u16* csr = a.csr[rel];
  int E = a.E[rel];
  for (int base = 0; base < E; base += 1024) {
#pragma unroll
    for (int u = 0; u < 4; ++u) {
      int e = base + u * 256 + threadIdx.x;
      if (e < E) {
        int d = dst[e] - w0;
        if ((unsigned)d < (unsigned)wn) {
          int pos = atomicAdd(&lcur[d], 1);
          csr[pos] = (u16)src[e];
        }
      }
    }
  }
}

// ---------------- GAT aggregate on RAW x; analytic pp self-loop ----------------
struct Agg5 {
  const u16* csr[5]; const int* starts[5];
  const float* ss[5]; const float* sd[5];
  const bf16_t* xs[5];
  bf16_t* y[5]; int ystride[5]; int ycoff[5]; int ndst[5]; int self[5];
};
__global__ __launch_bounds__(256) void k_agg5(Agg5 a) {
  int rel = blockIdx.y;
  int d = blockIdx.x * 4 + (threadIdx.x >> 6);
  if (d >= a.ndst[rel]) return;
  int lane = threadIdx.x & 63;
  int g = lane >> 4, j16 = lane & 15;
  bf16_t* yrow = a.y[rel] + (size_t)d * a.ystride[rel] + a.ycoff[rel];
  int s0 = a.starts[rel][d];
  int deg = a.starts[rel][d + 1] - s0;
  int selfa = a.self[rel];
  if (!deg && !selfa) {
    if (g == 0) *(uint4*)(yrow + j16 * 8) = make_uint4(0u, 0u, 0u, 0u);
    return;
  }
  const u16* cs = a.csr[rel] + s0;
  const float* ssp = a.ss[rel];
  const bf16_t* xsp = a.xs[rel];
  float sdv = a.sd[rel][d];
  float acc[8] = {0.f, 0.f, 0.f, 0.f, 0.f, 0.f, 0.f, 0.f};
  float ps = 0.f;
  for (int b = 0; b < deg; b += 16) {
#pragma unroll
    for (int u = 0; u < 4; ++u) {
      int i = b + u * 4 + g;
      float p = 0.f;
      uint4 U = make_uint4(0u, 0u, 0u, 0u);
      if (i < deg) {
        int s = cs[i];
        float e = ssp[s] + sdv; e = e > 0.f ? e : 0.2f * e;
        p = __expf(e);
        U = *(const uint4*)(xsp + (size_t)s * H + j16 * 8);
      }
      ps += p;
      acc[0] = fmaf(p, bflo(U.x), acc[0]); acc[1] = fmaf(p, bfhi(U.x), acc[1]);
      acc[2] = fmaf(p, bflo(U.y), acc[2]); acc[3] = fmaf(p, bfhi(U.y), acc[3]);
      acc[4] = fmaf(p, bflo(U.z), acc[4]); acc[5] = fmaf(p, bfhi(U.z), acc[5]);
      acc[6] = fmaf(p, bflo(U.w), acc[6]); acc[7] = fmaf(p, bfhi(U.w), acc[7]);
    }
  }
  if (selfa && g == 0) {
    float e = ssp[d] + sdv; e = e > 0.f ? e : 0.2f * e;
    float p = __expf(e);
    uint4 U = *(const uint4*)(xsp + (size_t)d * H + j16 * 8);
    ps += p;
    acc[0] = fmaf(p, bflo(U.x), acc[0]); acc[1] = fmaf(p, bfhi(U.x), acc[1]);
    acc[2] = fmaf(p, bflo(U.y), acc[2]); acc[3] = fmaf(p, bfhi(U.y), acc[3]);
    acc[4] = fmaf(p, bflo(U.z), acc[4]); acc[5] = fmaf(p, bfhi(U.z), acc[5]);
    acc[6] = fmaf(p, bflo(U.w), acc[6]); acc[7] = fmaf(p, bfhi(U.w), acc[7]);
  }
#pragma unroll
  for (int e = 0; e < 8; ++e) {
    acc[e] += __shfl_xor(acc[e], 16);
    acc[e] += __shfl_xor(acc[e], 32);
  }
  ps += __shfl_xor(ps, 16);
  ps += __shfl_xor(ps, 32);
  if (g == 0) {
    float inv = 1.f / ps;
    uint4 O;
    O.x = packbf(acc[0] * inv, acc[1] * inv);
    O.y = packbf(acc[2] * inv, acc[3] * inv);
    O.z = packbf(acc[4] * inv, acc[5] * inv);
    O.w = packbf(acc[6] * inv, acc[7] * inv);
    *(uint4*)(yrow + j16 * 8) = O;
  }
}

// ---------------- readout ----------------
__global__ __launch_bounds__(256) void k_invnorm(
    const bf16_t* __restrict__ xd, const bf16_t* __restrict__ xc,
    float* __restrict__ invd, float* __restrict__ invc)
{
  int row = blockIdx.x * 4 + (threadIdx.x >> 6);
  if (row >= ND + NCN) return;
  int lane = threadIdx.x & 63;
  const bf16_t* x = (row < ND) ? xd + (size_t)row * H : xc + (size_t)(row - ND) * H;
  unsigned u = ((const unsigned*)x)[lane];
  float av = bflo(u), bv = bfhi(u);
  float s = wred_sum(av * av + bv * bv);
  if (!lane) {
    float nv = fmaxf(sqrtf(s), 1e-12f);
    if (row < ND) invd[row] = 1.f / nv; else invc[row - ND] = 1.f / nv;
  }
}

// ================= host =================
extern "C" void kernel_launch(void* const* d_in, const int* in_sizes, int n_in,
                              void* d_out, int out_size, void* d_ws, size_t ws_size,
                              hipStream_t stream)
{
  (void)in_sizes; (void)n_in;
  const float* drug_emb    = (const float*)d_in[0];
  const float* protein_emb = (const float*)d_in[1];
  const float* cell_emb    = (const float*)d_in[2];
  // internal rel order: 0=dp, 1=pp, 2=cp, 3=rdp, 4=rcp
  const int base_idx[5] = {3, 11, 15, 7, 19};
  const float *W_[5], *as_[5], *ad_[5], *b_[5];
  for (int r = 0; r < 5; ++r) {
    W_[r]  = (const float*)d_in[base_idx[r]];
    as_[r] = (const float*)d_in[base_idx[r] + 1];
    ad_[r] = (const float*)d_in[base_idx[r] + 2];
    b_[r]  = (const float*)d_in[base_idx[r] + 3];
  }
  const float* W1 = (const float*)d_in[23]; const float* b1 = (const float*)d_in[24];
  const float* W2 = (const float*)d_in[25]; const float* b2 = (const float*)d_in[26];
  const float* W3 = (const float*)d_in[27]; const float* b3 = (const float*)d_in[28];
  const int* src_dp = (const int*)d_in[29]; const int* dst_dp = (const int*)d_in[30];
  const int* src_pp = (const int*)d_in[31]; const int* dst_pp = (const int*)d_in[32];
  const int* src_cp = (const int*)d_in[33]; const int* dst_cp = (const int*)d_in[34];
  const int* drug1  = (const int*)d_in[35]; const int* drug2  = (const int*)d_in[36];
  const int* cellb  = (const int*)d_in[37];
  float* out = (float*)d_out;

  char* wsb = (char*)d_ws;
  size_t off = 0;
  auto alloc = [&](size_t bytes) -> void* {
    void* p = wsb + off;
    off += (bytes + 255) & ~(size_t)255;
    return p;
  };
  bf16_t* xdb[2] = {(bf16_t*)alloc((size_t)ND * H * 2),  (bf16_t*)alloc((size_t)ND * H * 2)};
  bf16_t* xpb[2] = {(bf16_t*)alloc((size_t)NPN * H * 2), (bf16_t*)alloc((size_t)NPN * H * 2)};
  bf16_t* xcb[2] = {(bf16_t*)alloc((size_t)NCN * H * 2), (bf16_t*)alloc((size_t)NCN * H * 2)};
  const int Msrc[5] = {ND, NPN, NCN, NPN, NPN};
  const int Mdst[5] = {NPN, NPN, NPN, ND, NCN};
  const int Erel[5] = {E_DP, E_PP, E_CP, E_DP, E_CP};
  bf16_t* yp = (bf16_t*)alloc((size_t)NPN * 384 * 2);
  bf16_t* yd = (bf16_t*)alloc((size_t)ND * H * 2);
  bf16_t* yc = (bf16_t*)alloc((size_t)NCN * H * 2);
  bf16_t* Wtp = (bf16_t*)alloc((size_t)NLAYERS * 128 * 384 * 2);
  bf16_t* Wtd = (bf16_t*)alloc((size_t)NLAYERS * 128 * 128 * 2);
  bf16_t* Wtc = (bf16_t*)alloc((size_t)NLAYERS * 128 * 128 * 2);
  bf16_t* W1t = (bf16_t*)alloc((size_t)768 * 384 * 2);
  bf16_t* W2t = (bf16_t*)alloc((size_t)256 * 768 * 2);
  float* wvb = (float*)alloc(20 * H * 4);
  float* b1t = (float*)alloc(768 * 4);
  float* ssb[5]; for (int r = 0; r < 5; ++r) ssb[r] = (float*)alloc((size_t)Msrc[r] * 4);
  float* sdb[5]; for (int r = 0; r < 5; ++r) sdb[r] = (float*)alloc((size_t)Mdst[r] * 4);
  int* cnt_all = (int*)alloc(62000 * 4);
  int* st_all  = (int*)alloc((62000 + 5) * 4);
  int *cntb[5], *stb[5];
  { int o = 0, o2 = 0;
    for (int r = 0; r < 5; ++r) {
      cntb[r] = cnt_all + o; stb[r] = st_all + o2;
      o += Mdst[r]; o2 += Mdst[r] + 1;
    } }
  u16* csrb[5]; for (int r = 0; r < 5; ++r) csrb[r] = (u16*)alloc((size_t)Erel[r] * 2);
  float* invd = (float*)alloc(ND * 4);
  float* invc = (float*)alloc(NCN * 4);
  bf16_t* P1a = (bf16_t*)alloc((size_t)ND * 768 * 2);
  bf16_t* P1b = (bf16_t*)alloc((size_t)ND * 768 * 2);
  bf16_t* P1c = (bf16_t*)alloc((size_t)NCN * 768 * 2);
  (void)ws_size;

  // zero the output (fused head accumulates into it)
  hipMemsetAsync(out, 0, (size_t)out_size * 4, stream);

  // conversions
  k_conv_emb<<<(ND * H + NPN * H + NCN * H + 255) / 256, 256, 0, stream>>>(
      drug_emb, protein_emb, cell_emb, xdb[0], xpb[0], xcb[0]);
  k_scale3<<<3, 256, 0, stream>>>(b1, b1t);
  TC tc;
  for (int l = 0; l < 2; ++l) {
    for (int r = 0; r < 3; ++r) {
      int m = l * 3 + r;
      tc.src[m] = W_[r] + (size_t)l * H * H;
      tc.dst[m] = Wtp + (size_t)l * 128 * 384;
      tc.Ksub[m] = 128; tc.N[m] = 128; tc.Kfull[m] = 384; tc.koff[m] = r * 128;
    }
    tc.src[6 + l] = W_[3] + (size_t)l * H * H; tc.dst[6 + l] = Wtd + (size_t)l * 128 * 128;
    tc.Ksub[6 + l] = 128; tc.N[6 + l] = 128; tc.Kfull[6 + l] = 128; tc.koff[6 + l] = 0;
    tc.src[8 + l] = W_[4] + (size_t)l * H * H; tc.dst[8 + l] = Wtc + (size_t)l * 128 * 128;
    tc.Ksub[8 + l] = 128; tc.N[8 + l] = 128; tc.Kfull[8 + l] = 128; tc.koff[8 + l] = 0;
  }
  tc.src[10] = W1; tc.dst[10] = W1t; tc.Ksub[10] = 384; tc.N[10] = 768; tc.Kfull[10] = 384; tc.koff[10] = 0;
  tc.src[11] = W2; tc.dst[11] = W2t; tc.Ksub[11] = 768; tc.N[11] = 256; tc.Kfull[11] = 768; tc.koff[11] = 0;
  k_tconv2<<<dim3(24, 24, 12), 256, 0, stream>>>(tc);

  // wv for both layers
  Wd20 wg;
  for (int l = 0; l < 2; ++l)
    for (int r = 0; r < 5; ++r) {
      int m = l * 10 + r;
      wg.W[m] = W_[r] + (size_t)l * H * H; wg.a[m] = as_[r] + l * H; wg.o[m] = wvb + m * H;
      int m2 = l * 10 + 5 + r;
      wg.W[m2] = W_[r] + (size_t)l * H * H; wg.a[m2] = ad_[r] + l * H; wg.o[m2] = wvb + m2 * H;
    }
  k_wd20<<<20, 128, 0, stream>>>(wg);

  // CSR build: windowed count / scan / windowed fill (pp self-loops analytic)
  CsrW cw;
  const int* srcA[5] = {src_dp, src_pp, src_cp, dst_dp, dst_cp};
  const int* dstA[5] = {dst_dp, dst_pp, dst_cp, src_dp, src_cp};
  for (int r = 0; r < 5; ++r) {
    cw.src[r] = srcA[r]; cw.dst[r] = dstA[r]; cw.E[r] = Erel[r]; cw.n[r] = Mdst[r];
    cw.ws[r] = (Mdst[r] + NW - 1) / NW;
    cw.cnt[r] = cntb[r]; cw.starts[r] = stb[r]; cw.csr[r] = csrb[r];
  }
  k_countw<<<dim3(NW, 5), 256, 0, stream>>>(cw);
  k_scan5<<<5, 1024, 0, stream>>>(cw);
  k_fillw<<<dim3(NW, 5), 256, 0, stream>>>(cw);

  int cur = 0;
  for (int l = 0; l < NLAYERS; ++l) {
    int nxt = 1 - cur;
    const bf16_t* xsrc[5] = {xdb[cur], xpb[cur], xcb[cur], xpb[cur], xpb[cur]};
    Sc sc;
    sc.xd = xdb[cur]; sc.xp = xpb[cur]; sc.xc = xcb[cur]; sc.wv = wvb + l * 10 * H;
    for (int r = 0; r < 5; ++r) { sc.ss[r] = ssb[r]; sc.sd[r] = sdb[r]; }
    k_scores<<<(ND + NPN + NCN + 3) / 4, 256, 0, stream>>>(sc);
    Agg5 aa;
    bf16_t* yptr[5] = {yp, yp, yp, yd, yc};
    const int ystr[5] = {384, 384, 384, 128, 128};
    const int ycof[5] = {0, 128, 256, 0, 0};
    const int selfs[5] = {0, 1, 0, 0, 0};
    for (int r = 0; r < 5; ++r) {
      aa.csr[r] = csrb[r]; aa.starts[r] = stb[r]; aa.ss[r] = ssb[r]; aa.sd[r] = sdb[r];
      aa.xs[r] = xsrc[r]; aa.y[r] = yptr[r]; aa.ystride[r] = ystr[r]; aa.ycoff[r] = ycof[r];
      aa.ndst[r] = Mdst[r]; aa.self[r] = selfs[r];
    }
    k_agg5<<<dim3((NPN + 3) / 4, 5), 256, 0, stream>>>(aa);
    Gemm3 g3;
    g3.j[0] = {yp, Wtp + (size_t)l * 128 * 384, xpb[nxt], NPN, 384,
               b_[0] + l * H, b_[1] + l * H, b_[2] + l * H};
    g3.j[1] = {yd, Wtd + (size_t)l * 128 * 128, xdb[nxt], ND, 128,
               b_[3] + l * H, nullptr, nullptr};
    g3.j[2] = {yc, Wtc + (size_t)l * 128 * 128, xcb[nxt], NCN, 128,
               b_[4] + l * H, nullptr, nullptr};
    k_gemm_g3<<<dim3((NPN + 127) / 128, 3), 256, 0, stream>>>(g3);
    cur = nxt;
  }

  // head: inv-norms -> scaled slice GEMMs (bf16 P tables, b1/3 baked) -> fused gather+W2+W3
  k_invnorm<<<(ND + NCN + 3) / 4, 256, 0, stream>>>(xdb[cur], xcb[cur], invd, invc);
  GemmPS ps;
  ps.Bt = W1t; ps.b1t = b1t;
  ps.j[0] = {xdb[cur], P1a, ND, invd};
  ps.j[1] = {xdb[cur], P1b, ND, invd};
  ps.j[2] = {xcb[cur], P1c, NCN, invc};
  k_gemm_ps<<<dim3(32 * 6, 3), 256, 0, stream>>>(ps);
  k_w2head<<<(NB + 127) / 128, 256, 0, stream>>>(
      P1a, P1b, P1c, drug1, drug2, cellb, W2t, b2, W3, b3, out, NB);
}

// Round 10
// 405.819 us; speedup vs baseline: 2.6925x; 2.6925x over previous
//
#include <hip/hip_runtime.h>
#include <hip/hip_bf16.h>

#define H 128
#define ND 4000
#define NPN 19000
#define NCN 1000
#define NLAYERS 2
#define NB 30000
#define E_DP 200000
#define E_PP 300000
#define E_CP 150000

typedef __bf16 bf16_t;
typedef bf16_t bf16x8 __attribute__((ext_vector_type(8)));
typedef float f32x4 __attribute__((ext_vector_type(4)));
typedef unsigned short u16;

static __device__ __forceinline__ float wred_sum(float v) {
#pragma unroll
  for (int off = 32; off; off >>= 1) v += __shfl_xor(v, off);
  return v;
}
static __device__ __forceinline__ float bflo(unsigned u) { return __uint_as_float(u << 16); }
static __device__ __forceinline__ float bfhi(unsigned u) { return __uint_as_float(u & 0xffff0000u); }
static __device__ __forceinline__ unsigned packbf(float v0, float v1) {
  union { bf16_t b; unsigned short u; } a, b;
  a.b = (bf16_t)v0; b.b = (bf16_t)v1;
  return (unsigned)a.u | ((unsigned)b.u << 16);
}

// async global->LDS, 16B per lane
#define GLDS16(gp, lp) \
  __builtin_amdgcn_global_load_lds((__attribute__((address_space(1))) void*)(gp), \
                                   (__attribute__((address_space(3))) void*)(lp), 16, 0, 0)

// ================= MFMA GEMM core (fills acc; epilogue is per-kernel) =================
__device__ __forceinline__ void mfma_core(
    const bf16_t* __restrict__ A, const bf16_t* __restrict__ Bt,
    int M, int K, int ldb, int m0, int n0, f32x4 (&acc)[4][4])
{
  __shared__ char As[128 * 64];
  __shared__ char Bs[128 * 64];
  const int t = threadIdx.x;
  const int lane = t & 63;
#pragma unroll
  for (int mi = 0; mi < 4; ++mi)
#pragma unroll
    for (int ni = 0; ni < 4; ++ni) acc[mi][ni] = (f32x4){0.f, 0.f, 0.f, 0.f};

  const int wid = t >> 6;
  const int wr = wid >> 1, wc = wid & 1;
  const int sr = t >> 2;
  const int sc = t & 3;
  const int csrc = ((sc ^ ((sr >> 1) & 3)) << 4);
  int ra0 = m0 + sr;      if (ra0 >= M) ra0 = M - 1;
  int ra1 = m0 + 64 + sr; if (ra1 >= M) ra1 = M - 1;
  const char* gA0 = (const char*)A + (size_t)ra0 * K * 2 + csrc;
  const char* gA1 = (const char*)A + (size_t)ra1 * K * 2 + csrc;
  const char* gB0 = (const char*)Bt + (size_t)(n0 + sr) * ldb * 2 + csrc;
  const char* gB1 = (const char*)Bt + (size_t)(n0 + 64 + sr) * ldb * 2 + csrc;
  char* lA0 = As + t * 16;
  char* lA1 = As + 4096 + t * 16;
  char* lB0 = Bs + t * 16;
  char* lB1 = Bs + 4096 + t * 16;

  int aoff[4], boff[4];
#pragma unroll
  for (int mi = 0; mi < 4; ++mi) {
    int r = wr * 64 + mi * 16 + (lane & 15);
    aoff[mi] = r * 64 + ((((lane >> 4)) ^ ((r >> 1) & 3)) << 4);
  }
#pragma unroll
  for (int ni = 0; ni < 4; ++ni) {
    int r = wc * 64 + ni * 16 + (lane & 15);
    boff[ni] = r * 64 + ((((lane >> 4)) ^ ((r >> 1) & 3)) << 4);
  }

  for (int k0 = 0; k0 < K; k0 += 32) {
    const size_t kb = (size_t)k0 * 2;
    __syncthreads();
    GLDS16(gA0 + kb, lA0);
    GLDS16(gA1 + kb, lA1);
    GLDS16(gB0 + kb, lB0);
    GLDS16(gB1 + kb, lB1);
    __syncthreads();
    bf16x8 av[4], bv[4];
#pragma unroll
    for (int mi = 0; mi < 4; ++mi) av[mi] = *(const bf16x8*)(As + aoff[mi]);
#pragma unroll
    for (int ni = 0; ni < 4; ++ni) bv[ni] = *(const bf16x8*)(Bs + boff[ni]);
#pragma unroll
    for (int mi = 0; mi < 4; ++mi)
#pragma unroll
      for (int ni = 0; ni < 4; ++ni)
        acc[mi][ni] = __builtin_amdgcn_mfma_f32_16x16x32_bf16(av[mi], bv[ni], acc[mi][ni], 0, 0, 0);
  }
}

// --- GAT dst-side transform: C = relu(y @ Wt + biases), bf16 out, N=128 ---
struct GJob { const bf16_t* A; const bf16_t* Bt; bf16_t* C; int M; int K;
              const float *b1, *b2, *b3; };
struct Gemm3 { GJob j[3]; };
__global__ __launch_bounds__(256) void k_gemm_g3(Gemm3 g) {
  const GJob& jb = g.j[blockIdx.y];
  int m0 = blockIdx.x * 128;
  if (m0 >= jb.M) return;
  f32x4 acc[4][4];
  mfma_core(jb.A, jb.Bt, jb.M, jb.K, jb.K, m0, 0, acc);
  const int t = threadIdx.x, lane = t & 63, wid = t >> 6;
  const int wr = wid >> 1, wc = wid & 1;
  const int col0 = lane & 15, rsub = (lane >> 4) * 4;
#pragma unroll
  for (int mi = 0; mi < 4; ++mi) {
#pragma unroll
    for (int ni = 0; ni < 4; ++ni) {
      int c = wc * 64 + ni * 16 + col0;
      float bb = jb.b1[c];
      if (jb.b2) bb += jb.b2[c];
      if (jb.b3) bb += jb.b3[c];
#pragma unroll
      for (int rg = 0; rg < 4; ++rg) {
        int r = m0 + wr * 64 + mi * 16 + rsub + rg;
        if (r < jb.M) jb.C[(size_t)r * H + c] = (bf16_t)fmaxf(acc[mi][ni][rg] + bb, 0.f);
      }
    }
  }
}

// --- head slice GEMMs: P = (x @ W1slice) * rowscale + b1/3, bf16 out ---
struct PJob { const bf16_t* A; bf16_t* C; int M; const float* rs; };
struct GemmPS { PJob j[3]; const bf16_t* Bt; const float* b1t; };
__global__ __launch_bounds__(256) void k_gemm_ps(GemmPS g) {
  const PJob& jb = g.j[blockIdx.y];
  int mt = blockIdx.x / 6, nt = blockIdx.x - mt * 6;
  int m0 = mt * 128;
  if (m0 >= jb.M) return;
  int n0 = nt * 128;
  f32x4 acc[4][4];
  mfma_core(jb.A, g.Bt + blockIdx.y * 128, jb.M, 128, 384, m0, n0, acc);
  const int t = threadIdx.x, lane = t & 63, wid = t >> 6;
  const int wr = wid >> 1, wc = wid & 1;
  const int col0 = lane & 15, rsub = (lane >> 4) * 4;
#pragma unroll
  for (int mi = 0; mi < 4; ++mi) {
#pragma unroll
    for (int rg = 0; rg < 4; ++rg) {
      int r = m0 + wr * 64 + mi * 16 + rsub + rg;
      if (r < jb.M) {
        float sc = jb.rs[r];
#pragma unroll
        for (int ni = 0; ni < 4; ++ni) {
          int c = n0 + wc * 64 + ni * 16 + col0;
          jb.C[(size_t)r * 768 + c] = (bf16_t)(acc[mi][ni][rg] * sc + g.b1t[c]);
        }
      }
    }
  }
}

// --- fused head, BN=256 single pass ---
__global__ __launch_bounds__(256) void k_w2head(
    const bf16_t* __restrict__ Pa, const bf16_t* __restrict__ Pb, const bf16_t* __restrict__ Pc,
    const int* __restrict__ d1, const int* __restrict__ d2, const int* __restrict__ ce,
    const bf16_t* __restrict__ W2t, const float* __restrict__ b2,
    const float* __restrict__ W3, const float* __restrict__ b3,
    float* __restrict__ out, int cn)
{
  __shared__ char As[128 * 64];
  __shared__ char Bs[256 * 64];
  const int t = threadIdx.x;
  const int lane = t & 63;
  const int m0 = blockIdx.x * 128;
  if (m0 >= cn) return;
  f32x4 acc[4][8];
#pragma unroll
  for (int mi = 0; mi < 4; ++mi)
#pragma unroll
    for (int ni = 0; ni < 8; ++ni) acc[mi][ni] = (f32x4){0.f, 0.f, 0.f, 0.f};

  const int arow = t >> 1;
  const int ah = t & 1;
  int gr = m0 + arow; if (gr >= cn) gr = cn - 1;
  const bf16_t* pa = Pa + (size_t)d1[gr] * 768 + ah * 16;
  const bf16_t* pb = Pb + (size_t)d2[gr] * 768 + ah * 16;
  const bf16_t* pc = Pc + (size_t)ce[gr] * 768 + ah * 16;
  const int swz = (arow >> 1) & 3;
  char* la0 = As + arow * 64 + (((ah * 2)     ^ swz) << 4);
  char* la1 = As + arow * 64 + (((ah * 2 + 1) ^ swz) << 4);

  const int sr = t >> 2;
  const int sc = t & 3;
  const int csrc = ((sc ^ ((sr >> 1) & 3)) << 4);
  const char* gB = (const char*)W2t + (size_t)sr * 768 * 2 + csrc;
  const size_t qstep = (size_t)64 * 768 * 2;

  const int wid = t >> 6;
  const int wr = wid >> 1, wc = wid & 1;
  int aoff[4], boff[8];
#pragma unroll
  for (int mi = 0; mi < 4; ++mi) {
    int r = wr * 64 + mi * 16 + (lane & 15);
    aoff[mi] = r * 64 + ((((lane >> 4)) ^ ((r >> 1) & 3)) << 4);
  }
#pragma unroll
  for (int ni = 0; ni < 8; ++ni) {
    int r = wc * 128 + ni * 16 + (lane & 15);
    boff[ni] = r * 64 + ((((lane >> 4)) ^ ((r >> 1) & 3)) << 4);
  }

#define ACC8(U, o) { s[o+0] += bflo(U.x); s[o+1] += bfhi(U.x); s[o+2] += bflo(U.y); s[o+3] += bfhi(U.y); \
                     s[o+4] += bflo(U.z); s[o+5] += bfhi(U.z); s[o+6] += bflo(U.w); s[o+7] += bfhi(U.w); }
  for (int k0 = 0; k0 < 768; k0 += 32) {
    uint4 Ua0 = *(const uint4*)(pa + k0);
    uint4 Ua1 = *(const uint4*)(pa + k0 + 8);
    uint4 Ub0 = *(const uint4*)(pb + k0);
    uint4 Ub1 = *(const uint4*)(pb + k0 + 8);
    uint4 Uc0 = *(const uint4*)(pc + k0);
    uint4 Uc1 = *(const uint4*)(pc + k0 + 8);
    float s[16] = {0.f, 0.f, 0.f, 0.f, 0.f, 0.f, 0.f, 0.f,
                   0.f, 0.f, 0.f, 0.f, 0.f, 0.f, 0.f, 0.f};
    ACC8(Ua0, 0) ACC8(Ua1, 8)
    ACC8(Ub0, 0) ACC8(Ub1, 8)
    ACC8(Uc0, 0) ACC8(Uc1, 8)
    uint4 P0, P1;
    P0.x = packbf(fmaxf(s[0], 0.f),  fmaxf(s[1], 0.f));
    P0.y = packbf(fmaxf(s[2], 0.f),  fmaxf(s[3], 0.f));
    P0.z = packbf(fmaxf(s[4], 0.f),  fmaxf(s[5], 0.f));
    P0.w = packbf(fmaxf(s[6], 0.f),  fmaxf(s[7], 0.f));
    P1.x = packbf(fmaxf(s[8], 0.f),  fmaxf(s[9], 0.f));
    P1.y = packbf(fmaxf(s[10], 0.f), fmaxf(s[11], 0.f));
    P1.z = packbf(fmaxf(s[12], 0.f), fmaxf(s[13], 0.f));
    P1.w = packbf(fmaxf(s[14], 0.f), fmaxf(s[15], 0.f));
    const size_t kb = (size_t)k0 * 2;
    __syncthreads();
    GLDS16(gB + kb,             Bs + t * 16);
    GLDS16(gB + qstep + kb,     Bs + 4096 + t * 16);
    GLDS16(gB + 2 * qstep + kb, Bs + 8192 + t * 16);
    GLDS16(gB + 3 * qstep + kb, Bs + 12288 + t * 16);
    *(uint4*)la0 = P0;
    *(uint4*)la1 = P1;
    __syncthreads();
    bf16x8 av[4], bv[8];
#pragma unroll
    for (int mi = 0; mi < 4; ++mi) av[mi] = *(const bf16x8*)(As + aoff[mi]);
#pragma unroll
    for (int ni = 0; ni < 8; ++ni) bv[ni] = *(const bf16x8*)(Bs + boff[ni]);
#pragma unroll
    for (int mi = 0; mi < 4; ++mi)
#pragma unroll
      for (int ni = 0; ni < 8; ++ni)
        acc[mi][ni] = __builtin_amdgcn_mfma_f32_16x16x32_bf16(av[mi], bv[ni], acc[mi][ni], 0, 0, 0);
  }
#undef ACC8

  const int col0 = lane & 15, rsub = (lane >> 4) * 4;
  float w0[8], w1[8], bb[8];
#pragma unroll
  for (int ni = 0; ni < 8; ++ni) {
    int c = wc * 128 + ni * 16 + col0;
    w0[ni] = W3[2 * c]; w1[ni] = W3[2 * c + 1]; bb[ni] = b2[c];
  }
#pragma unroll
  for (int mi = 0; mi < 4; ++mi) {
#pragma unroll
    for (int rg = 0; rg < 4; ++rg) {
      int r = m0 + wr * 64 + mi * 16 + rsub + rg;
      float p0 = 0.f, p1 = 0.f;
#pragma unroll
      for (int ni = 0; ni < 8; ++ni) {
        float v = fmaxf(acc[mi][ni][rg] + bb[ni], 0.f);
        p0 = fmaf(v, w0[ni], p0);
        p1 = fmaf(v, w1[ni], p1);
      }
#pragma unroll
      for (int off = 1; off < 16; off <<= 1) {
        p0 += __shfl_xor(p0, off);
        p1 += __shfl_xor(p1, off);
      }
      if (col0 == 0 && r < cn) {
        if (wc == 0) { p0 += b3[0]; p1 += b3[1]; }
        atomicAdd(&out[(size_t)r * 2], p0);
        atomicAdd(&out[(size_t)r * 2 + 1], p1);
      }
    }
  }
}

// ================= conversions (emb->bf16 + b1/3 fused) =================
__global__ __launch_bounds__(256) void k_conv_emb(
    const float* __restrict__ xd, const float* __restrict__ xp, const float* __restrict__ xc,
    bf16_t* __restrict__ od, bf16_t* __restrict__ op, bf16_t* __restrict__ oc,
    const float* __restrict__ b1, float* __restrict__ b1t)
{
  int i = blockIdx.x * 256 + threadIdx.x;
  const int SD = ND * H, SP = NPN * H, SC = NCN * H;
  if (i < SD) od[i] = (bf16_t)xd[i];
  else if (i < SD + SP) op[i - SD] = (bf16_t)xp[i - SD];
  else if (i < SD + SP + SC) oc[i - SD - SP] = (bf16_t)xc[i - SD - SP];
  else if (i < SD + SP + SC + 768) { int j = i - SD - SP - SC; b1t[j] = b1[j] * (1.f / 3.f); }
}

// LDS-tiled transpose-convert: dst[n*Kfull+koff+k] = bf16(src[k*N+n])
struct TC { const float* src[12]; bf16_t* dst[12]; int Ksub[12]; int N[12]; int Kfull[12]; int koff[12]; };
__global__ __launch_bounds__(256) void k_tconv2(TC a) {
  int m = blockIdx.z;
  int Ks = a.Ksub[m], N = a.N[m];
  int tx = blockIdx.x * 32;
  int ty = blockIdx.y * 32;
  if (tx >= N || ty >= Ks) return;
  __shared__ float tile[32][33];
  int c = threadIdx.x & 31, rr = threadIdx.x >> 5;
#pragma unroll
  for (int kk = rr; kk < 32; kk += 8)
    if (ty + kk < Ks && tx + c < N) tile[kk][c] = a.src[m][(size_t)(ty + kk) * N + tx + c];
  __syncthreads();
  bf16_t* dst = a.dst[m];
  int Kf = a.Kfull[m], ko = a.koff[m];
#pragma unroll
  for (int nn = rr; nn < 32; nn += 8)
    if (tx + nn < N && ty + c < Ks)
      dst[(size_t)(tx + nn) * Kf + ko + ty + c] = (bf16_t)tile[c][nn];
}

// ---------------- wv = W @ a : both layers, 20 matvecs ----------------
struct Wd20 { const float* W[20]; const float* a[20]; float* o[20]; };
__global__ __launch_bounds__(128) void k_wd20(Wd20 g) {
  int m = blockIdx.x;
  int k = threadIdx.x;
  const float* Wp = g.W[m];
  const float* av = g.a[m];
  float s = 0.f;
#pragma unroll 4
  for (int j = 0; j < H; ++j) s = fmaf(Wp[k * H + j], av[j], s);
  g.o[m][k] = s;
}

// ---------------- fused node scores ----------------
struct Sc { const bf16_t* xd; const bf16_t* xp; const bf16_t* xc; const float* wv;
            float* ss[5]; float* sd[5]; };
__global__ __launch_bounds__(256) void k_scores(Sc S) {
  int row = blockIdx.x * 4 + (threadIdx.x >> 6);
  if (row >= ND + NPN + NCN) return;
  int lane = threadIdx.x & 63;
  const bf16_t* x;
  int idx, cls;
  if (row < ND) { x = S.xd; idx = row; cls = 0; }
  else if (row < ND + NPN) { x = S.xp; idx = row - ND; cls = 1; }
  else { x = S.xc; idx = row - ND - NPN; cls = 2; }
  unsigned u = *(const unsigned*)(x + (size_t)idx * H + lane * 2);
  float x0 = bflo(u), x1 = bfhi(u);
  const float* wv = S.wv;
#define DOT(vi, outp) { const float* v = wv + (vi) * H; \
    float s = x0 * v[2 * lane] + x1 * v[2 * lane + 1]; s = wred_sum(s); \
    if (!lane) (outp)[idx] = s; }
  if (cls == 0) {
    DOT(0, S.ss[0]); DOT(8, S.sd[3]);
  } else if (cls == 1) {
    DOT(1, S.ss[1]); DOT(3, S.ss[3]); DOT(4, S.ss[4]);
    DOT(5, S.sd[0]); DOT(6, S.sd[1]); DOT(7, S.sd[2]);
  } else {
    DOT(2, S.ss[2]); DOT(9, S.sd[4]);
  }
#undef DOT
}

// ---------------- CSR build (u16 payload, 4-edge ILP, nt stores) ----------------
struct CsrArgs {
  const int* src[5]; const int* dst[5];
  int E[5]; int n[5];
  int* cnt[5]; int* cur[5]; int* starts[5]; u16* csr[5];
};
__global__ __launch_bounds__(256) void k_count5(CsrArgs a) {
  int rel = blockIdx.y;
  int E = a.E[rel];
  const int* dst = a.dst[rel];
  int* cnt = a.cnt[rel];
  int e0 = blockIdx.x * 1024 + threadIdx.x;
#pragma unroll
  for (int u = 0; u < 4; ++u) {
    int e = e0 + u * 256;
    if (e < E) atomicAdd(&cnt[dst[e]], 1);
  }
}
__global__ __launch_bounds__(1024) void k_scan5(CsrArgs a) {
  int rel = blockIdx.x;
  int n = a.n[rel];
  const int* cnt = a.cnt[rel];
  int* st = a.starts[rel];
  int* cu = a.cur[rel];
  int t = threadIdx.x;
  int stripe = (n + 1023) / 1024;
  int lo = t * stripe;
  int hi = lo + stripe; if (hi > n) hi = n;
  int s = 0;
  for (int i = lo; i < hi; ++i) s += cnt[i];
  int lane = t & 63, wv = t >> 6;
  int x = s;
#pragma unroll
  for (int off = 1; off < 64; off <<= 1) {
    int y = __shfl_up(x, off);
    if (lane >= off) x += y;
  }
  __shared__ int ws[16];
  if (lane == 63) ws[wv] = x;
  __syncthreads();
  if (t == 0) {
    int run = 0;
#pragma unroll
    for (int i = 0; i < 16; ++i) { int v = ws[i]; ws[i] = run; run += v; }
  }
  __syncthreads();
  int run = ws[wv] + x - s;
  for (int i = lo; i < hi; ++i) { st[i] = run; cu[i] = run; run += cnt[i]; }
  if (t == 1023) st[n] = ws[15] + x;
}
__global__ __launch_bounds__(256) void k_fill5(CsrArgs a) {
  int rel = blockIdx.y;
  int E = a.E[rel];
  const int* dst = a.dst[rel];
  const int* src = a.src[rel];
  int* cur = a.cur[rel];
  u16* csr = a.csr[rel];
  int e0 = blockIdx.x * 1024 + threadIdx.x;
#pragma unroll
  for (int u = 0; u < 4; ++u) {
    int e = e0 + u * 256;
    if (e < E) {
      int pos = atomicAdd(&cur[dst[e]], 1);
      __builtin_nontemporal_store((u16)src[e], &csr[pos]);
    }
  }
}

// ---------------- GAT aggregate on RAW x; analytic pp self-loop ----------------
struct Agg5 {
  const u16* csr[5]; const int* starts[5];
  const float* ss[5]; const float* sd[5];
  const bf16_t* xs[5];
  bf16_t* y[5]; int ystride[5]; int ycoff[5]; int ndst[5]; int self[5];
};
__global__ __launch_bounds__(256) void k_agg5(Agg5 a) {
  int rel = blockIdx.y;
  int d = blockIdx.x * 4 + (threadIdx.x >> 6);
  if (d >= a.ndst[rel]) return;
  int lane = threadIdx.x & 63;
  int g = lane >> 4, j16 = lane & 15;
  bf16_t* yrow = a.y[rel] + (size_t)d * a.ystride[rel] + a.ycoff[rel];
  int s0 = a.starts[rel][d];
  int deg = a.starts[rel][d + 1] - s0;
  int selfa = a.self[rel];
  if (!deg && !selfa) {
    if (g == 0) *(uint4*)(yrow + j16 * 8) = make_uint4(0u, 0u, 0u, 0u);
    return;
  }
  const u16* cs = a.csr[rel] + s0;
  const float* ssp = a.ss[rel];
  const bf16_t* xsp = a.xs[rel];
  float sdv = a.sd[rel][d];
  float acc[8] = {0.f, 0.f, 0.f, 0.f, 0.f, 0.f, 0.f, 0.f};
  float ps = 0.f;
  for (int b = 0; b < deg; b += 16) {
#pragma unroll
    for (int u = 0; u < 4; ++u) {
      int i = b + u * 4 + g;
      float p = 0.f;
      uint4 U = make_uint4(0u, 0u, 0u, 0u);
      if (i < deg) {
        int s = cs[i];
        float e = ssp[s] + sdv; e = e > 0.f ? e : 0.2f * e;
        p = __expf(e);
        U = *(const uint4*)(xsp + (size_t)s * H + j16 * 8);
      }
      ps += p;
      acc[0] = fmaf(p, bflo(U.x), acc[0]); acc[1] = fmaf(p, bfhi(U.x), acc[1]);
      acc[2] = fmaf(p, bflo(U.y), acc[2]); acc[3] = fmaf(p, bfhi(U.y), acc[3]);
      acc[4] = fmaf(p, bflo(U.z), acc[4]); acc[5] = fmaf(p, bfhi(U.z), acc[5]);
      acc[6] = fmaf(p, bflo(U.w), acc[6]); acc[7] = fmaf(p, bfhi(U.w), acc[7]);
    }
  }
  if (selfa && g == 0) {
    float e = ssp[d] + sdv; e = e > 0.f ? e : 0.2f * e;
    float p = __expf(e);
    uint4 U = *(const uint4*)(xsp + (size_t)d * H + j16 * 8);
    ps += p;
    acc[0] = fmaf(p, bflo(U.x), acc[0]); acc[1] = fmaf(p, bfhi(U.x), acc[1]);
    acc[2] = fmaf(p, bflo(U.y), acc[2]); acc[3] = fmaf(p, bfhi(U.y), acc[3]);
    acc[4] = fmaf(p, bflo(U.z), acc[4]); acc[5] = fmaf(p, bfhi(U.z), acc[5]);
    acc[6] = fmaf(p, bflo(U.w), acc[6]); acc[7] = fmaf(p, bfhi(U.w), acc[7]);
  }
#pragma unroll
  for (int e = 0; e < 8; ++e) {
    acc[e] += __shfl_xor(acc[e], 16);
    acc[e] += __shfl_xor(acc[e], 32);
  }
  ps += __shfl_xor(ps, 16);
  ps += __shfl_xor(ps, 32);
  if (g == 0) {
    float inv = 1.f / ps;
    uint4 O;
    O.x = packbf(acc[0] * inv, acc[1] * inv);
    O.y = packbf(acc[2] * inv, acc[3] * inv);
    O.z = packbf(acc[4] * inv, acc[5] * inv);
    O.w = packbf(acc[6] * inv, acc[7] * inv);
    *(uint4*)(yrow + j16 * 8) = O;
  }
}

// ---------------- readout ----------------
__global__ __launch_bounds__(256) void k_invnorm(
    const bf16_t* __restrict__ xd, const bf16_t* __restrict__ xc,
    float* __restrict__ invd, float* __restrict__ invc)
{
  int row = blockIdx.x * 4 + (threadIdx.x >> 6);
  if (row >= ND + NCN) return;
  int lane = threadIdx.x & 63;
  const bf16_t* x = (row < ND) ? xd + (size_t)row * H : xc + (size_t)(row - ND) * H;
  unsigned u = ((const unsigned*)x)[lane];
  float av = bflo(u), bv = bfhi(u);
  float s = wred_sum(av * av + bv * bv);
  if (!lane) {
    float nv = fmaxf(sqrtf(s), 1e-12f);
    if (row < ND) invd[row] = 1.f / nv; else invc[row - ND] = 1.f / nv;
  }
}

// ================= host =================
extern "C" void kernel_launch(void* const* d_in, const int* in_sizes, int n_in,
                              void* d_out, int out_size, void* d_ws, size_t ws_size,
                              hipStream_t stream)
{
  (void)in_sizes; (void)n_in;
  const float* drug_emb    = (const float*)d_in[0];
  const float* protein_emb = (const float*)d_in[1];
  const float* cell_emb    = (const float*)d_in[2];
  // internal rel order: 0=dp, 1=pp, 2=cp, 3=rdp, 4=rcp
  const int base_idx[5] = {3, 11, 15, 7, 19};
  const float *W_[5], *as_[5], *ad_[5], *b_[5];
  for (int r = 0; r < 5; ++r) {
    W_[r]  = (const float*)d_in[base_idx[r]];
    as_[r] = (const float*)d_in[base_idx[r] + 1];
    ad_[r] = (const float*)d_in[base_idx[r] + 2];
    b_[r]  = (const float*)d_in[base_idx[r] + 3];
  }
  const float* W1 = (const float*)d_in[23]; const float* b1 = (const float*)d_in[24];
  const float* W2 = (const float*)d_in[25]; const float* b2 = (const float*)d_in[26];
  const float* W3 = (const float*)d_in[27]; const float* b3 = (const float*)d_in[28];
  const int* src_dp = (const int*)d_in[29]; const int* dst_dp = (const int*)d_in[30];
  const int* src_pp = (const int*)d_in[31]; const int* dst_pp = (const int*)d_in[32];
  const int* src_cp = (const int*)d_in[33]; const int* dst_cp = (const int*)d_in[34];
  const int* drug1  = (const int*)d_in[35]; const int* drug2  = (const int*)d_in[36];
  const int* cellb  = (const int*)d_in[37];
  float* out = (float*)d_out;

  char* wsb = (char*)d_ws;
  size_t off = 0;
  auto alloc = [&](size_t bytes) -> void* {
    void* p = wsb + off;
    off += (bytes + 255) & ~(size_t)255;
    return p;
  };
  bf16_t* xdb[2] = {(bf16_t*)alloc((size_t)ND * H * 2),  (bf16_t*)alloc((size_t)ND * H * 2)};
  bf16_t* xpb[2] = {(bf16_t*)alloc((size_t)NPN * H * 2), (bf16_t*)alloc((size_t)NPN * H * 2)};
  bf16_t* xcb[2] = {(bf16_t*)alloc((size_t)NCN * H * 2), (bf16_t*)alloc((size_t)NCN * H * 2)};
  const int Msrc[5] = {ND, NPN, NCN, NPN, NPN};
  const int Mdst[5] = {NPN, NPN, NPN, ND, NCN};
  const int Erel[5] = {E_DP, E_PP, E_CP, E_DP, E_CP};
  bf16_t* yp = (bf16_t*)alloc((size_t)NPN * 384 * 2);
  bf16_t* yd = (bf16_t*)alloc((size_t)ND * H * 2);
  bf16_t* yc = (bf16_t*)alloc((size_t)NCN * H * 2);
  bf16_t* Wtp = (bf16_t*)alloc((size_t)NLAYERS * 128 * 384 * 2);
  bf16_t* Wtd = (bf16_t*)alloc((size_t)NLAYERS * 128 * 128 * 2);
  bf16_t* Wtc = (bf16_t*)alloc((size_t)NLAYERS * 128 * 128 * 2);
  bf16_t* W1t = (bf16_t*)alloc((size_t)768 * 384 * 2);
  bf16_t* W2t = (bf16_t*)alloc((size_t)256 * 768 * 2);
  float* wvb = (float*)alloc(20 * H * 4);
  float* b1t = (float*)alloc(768 * 4);
  float* ssb[5]; for (int r = 0; r < 5; ++r) ssb[r] = (float*)alloc((size_t)Msrc[r] * 4);
  float* sdb[5]; for (int r = 0; r < 5; ++r) sdb[r] = (float*)alloc((size_t)Mdst[r] * 4);
  int* cnt_all = (int*)alloc(62000 * 4);
  int* cur_all = (int*)alloc(62000 * 4);
  int* st_all  = (int*)alloc((62000 + 5) * 4);
  int *cntb[5], *curb[5], *stb[5];
  { int o = 0, o2 = 0;
    for (int r = 0; r < 5; ++r) {
      cntb[r] = cnt_all + o; curb[r] = cur_all + o; stb[r] = st_all + o2;
      o += Mdst[r]; o2 += Mdst[r] + 1;
    } }
  u16* csrb[5]; for (int r = 0; r < 5; ++r) csrb[r] = (u16*)alloc((size_t)Erel[r] * 2);
  float* invd = (float*)alloc(ND * 4);
  float* invc = (float*)alloc(NCN * 4);
  bf16_t* P1a = (bf16_t*)alloc((size_t)ND * 768 * 2);
  bf16_t* P1b = (bf16_t*)alloc((size_t)ND * 768 * 2);
  bf16_t* P1c = (bf16_t*)alloc((size_t)NCN * 768 * 2);
  (void)ws_size;

  // zero the output (fused head accumulates into it)
  hipMemsetAsync(out, 0, (size_t)out_size * 4, stream);

  // conversions (+ b1/3)
  k_conv_emb<<<(ND * H + NPN * H + NCN * H + 768 + 255) / 256, 256, 0, stream>>>(
      drug_emb, protein_emb, cell_emb, xdb[0], xpb[0], xcb[0], b1, b1t);
  TC tc;
  for (int l = 0; l < 2; ++l) {
    for (int r = 0; r < 3; ++r) {
      int m = l * 3 + r;
      tc.src[m] = W_[r] + (size_t)l * H * H;
      tc.dst[m] = Wtp + (size_t)l * 128 * 384;
      tc.Ksub[m] = 128; tc.N[m] = 128; tc.Kfull[m] = 384; tc.koff[m] = r * 128;
    }
    tc.src[6 + l] = W_[3] + (size_t)l * H * H; tc.dst[6 + l] = Wtd + (size_t)l * 128 * 128;
    tc.Ksub[6 + l] = 128; tc.N[6 + l] = 128; tc.Kfull[6 + l] = 128; tc.koff[6 + l] = 0;
    tc.src[8 + l] = W_[4] + (size_t)l * H * H; tc.dst[8 + l] = Wtc + (size_t)l * 128 * 128;
    tc.Ksub[8 + l] = 128; tc.N[8 + l] = 128; tc.Kfull[8 + l] = 128; tc.koff[8 + l] = 0;
  }
  tc.src[10] = W1; tc.dst[10] = W1t; tc.Ksub[10] = 384; tc.N[10] = 768; tc.Kfull[10] = 384; tc.koff[10] = 0;
  tc.src[11] = W2; tc.dst[11] = W2t; tc.Ksub[11] = 768; tc.N[11] = 256; tc.Kfull[11] = 768; tc.koff[11] = 0;
  k_tconv2<<<dim3(24, 24, 12), 256, 0, stream>>>(tc);

  // wv for both layers
  Wd20 wg;
  for (int l = 0; l < 2; ++l)
    for (int r = 0; r < 5; ++r) {
      int m = l * 10 + r;
      wg.W[m] = W_[r] + (size_t)l * H * H; wg.a[m] = as_[r] + l * H; wg.o[m] = wvb + m * H;
      int m2 = l * 10 + 5 + r;
      wg.W[m2] = W_[r] + (size_t)l * H * H; wg.a[m2] = ad_[r] + l * H; wg.o[m2] = wvb + m2 * H;
    }
  k_wd20<<<20, 128, 0, stream>>>(wg);

  // CSR build (u16; pp WITHOUT self-loops — handled analytically in agg)
  hipMemsetAsync(cnt_all, 0, 62000 * 4, stream);
  CsrArgs ca;
  const int* srcA[5] = {src_dp, src_pp, src_cp, dst_dp, dst_cp};
  const int* dstA[5] = {dst_dp, dst_pp, dst_cp, src_dp, src_cp};
  for (int r = 0; r < 5; ++r) {
    ca.src[r] = srcA[r]; ca.dst[r] = dstA[r]; ca.E[r] = Erel[r]; ca.n[r] = Mdst[r];
    ca.cnt[r] = cntb[r]; ca.cur[r] = curb[r]; ca.starts[r] = stb[r]; ca.csr[r] = csrb[r];
  }
  dim3 egrid((E_PP + 1023) / 1024, 5);
  k_count5<<<egrid, 256, 0, stream>>>(ca);
  k_scan5<<<5, 1024, 0, stream>>>(ca);
  k_fill5<<<egrid, 256, 0, stream>>>(ca);

  int cur = 0;
  for (int l = 0; l < NLAYERS; ++l) {
    int nxt = 1 - cur;
    const bf16_t* xsrc[5] = {xdb[cur], xpb[cur], xcb[cur], xpb[cur], xpb[cur]};
    Sc sc;
    sc.xd = xdb[cur]; sc.xp = xpb[cur]; sc.xc = xcb[cur]; sc.wv = wvb + l * 10 * H;
    for (int r = 0; r < 5; ++r) { sc.ss[r] = ssb[r]; sc.sd[r] = sdb[r]; }
    k_scores<<<(ND + NPN + NCN + 3) / 4, 256, 0, stream>>>(sc);
    Agg5 aa;
    bf16_t* yptr[5] = {yp, yp, yp, yd, yc};
    const int ystr[5] = {384, 384, 384, 128, 128};
    const int ycof[5] = {0, 128, 256, 0, 0};
    const int selfs[5] = {0, 1, 0, 0, 0};
    for (int r = 0; r < 5; ++r) {
      aa.csr[r] = csrb[r]; aa.starts[r] = stb[r]; aa.ss[r] = ssb[r]; aa.sd[r] = sdb[r];
      aa.xs[r] = xsrc[r]; aa.y[r] = yptr[r]; aa.ystride[r] = ystr[r]; aa.ycoff[r] = ycof[r];
      aa.ndst[r] = Mdst[r]; aa.self[r] = selfs[r];
    }
    k_agg5<<<dim3((NPN + 3) / 4, 5), 256, 0, stream>>>(aa);
    Gemm3 g3;
    g3.j[0] = {yp, Wtp + (size_t)l * 128 * 384, xpb[nxt], NPN, 384,
               b_[0] + l * H, b_[1] + l * H, b_[2] + l * H};
    g3.j[1] = {yd, Wtd + (size_t)l * 128 * 128, xdb[nxt], ND, 128,
               b_[3] + l * H, nullptr, nullptr};
    g3.j[2] = {yc, Wtc + (size_t)l * 128 * 128, xcb[nxt], NCN, 128,
               b_[4] + l * H, nullptr, nullptr};
    k_gemm_g3<<<dim3((NPN + 127) / 128, 3), 256, 0, stream>>>(g3);
    cur = nxt;
  }

  // head: inv-norms -> scaled slice GEMMs (bf16 P tables, b1/3 baked) -> fused gather+W2+W3
  k_invnorm<<<(ND + NCN + 3) / 4, 256, 0, stream>>>(xdb[cur], xcb[cur], invd, invc);
  GemmPS ps;
  ps.Bt = W1t; ps.b1t = b1t;
  ps.j[0] = {xdb[cur], P1a, ND, invd};
  ps.j[1] = {xdb[cur], P1b, ND, invd};
  ps.j[2] = {xcb[cur], P1c, NCN, invc};
  k_gemm_ps<<<dim3(32 * 6, 3), 256, 0, stream>>>(ps);
  k_w2head<<<(NB + 127) / 128, 256, 0, stream>>>(
      P1a, P1b, P1c, drug1, drug2, cellb, W2t, b2, W3, b3, out, NB);
}

// Round 11
// 383.967 us; speedup vs baseline: 2.8457x; 1.0569x over previous
//
#include <hip/hip_runtime.h>
#include <hip/hip_bf16.h>

#define H 128
#define ND 4000
#define NPN 19000
#define NCN 1000
#define NLAYERS 2
#define NB 30000
#define E_DP 200000
#define E_PP 300000
#define E_CP 150000

typedef __bf16 bf16_t;
typedef bf16_t bf16x8 __attribute__((ext_vector_type(8)));
typedef float f32x4 __attribute__((ext_vector_type(4)));
typedef unsigned short u16;

static __device__ __forceinline__ float wred_sum(float v) {
#pragma unroll
  for (int off = 32; off; off >>= 1) v += __shfl_xor(v, off);
  return v;
}
static __device__ __forceinline__ float bflo(unsigned u) { return __uint_as_float(u << 16); }
static __device__ __forceinline__ float bfhi(unsigned u) { return __uint_as_float(u & 0xffff0000u); }
static __device__ __forceinline__ unsigned packbf(float v0, float v1) {
  union { bf16_t b; unsigned short u; } a, b;
  a.b = (bf16_t)v0; b.b = (bf16_t)v1;
  return (unsigned)a.u | ((unsigned)b.u << 16);
}

// async global->LDS, 16B per lane
#define GLDS16(gp, lp) \
  __builtin_amdgcn_global_load_lds((__attribute__((address_space(1))) void*)(gp), \
                                   (__attribute__((address_space(3))) void*)(lp), 16, 0, 0)

// ================= MFMA GEMM core (fills acc; epilogue is per-kernel) =================
__device__ __forceinline__ void mfma_core(
    const bf16_t* __restrict__ A, const bf16_t* __restrict__ Bt,
    int M, int K, int ldb, int m0, int n0, f32x4 (&acc)[4][4])
{
  __shared__ char As[128 * 64];
  __shared__ char Bs[128 * 64];
  const int t = threadIdx.x;
  const int lane = t & 63;
#pragma unroll
  for (int mi = 0; mi < 4; ++mi)
#pragma unroll
    for (int ni = 0; ni < 4; ++ni) acc[mi][ni] = (f32x4){0.f, 0.f, 0.f, 0.f};

  const int wid = t >> 6;
  const int wr = wid >> 1, wc = wid & 1;
  const int sr = t >> 2;
  const int sc = t & 3;
  const int csrc = ((sc ^ ((sr >> 1) & 3)) << 4);
  int ra0 = m0 + sr;      if (ra0 >= M) ra0 = M - 1;
  int ra1 = m0 + 64 + sr; if (ra1 >= M) ra1 = M - 1;
  const char* gA0 = (const char*)A + (size_t)ra0 * K * 2 + csrc;
  const char* gA1 = (const char*)A + (size_t)ra1 * K * 2 + csrc;
  const char* gB0 = (const char*)Bt + (size_t)(n0 + sr) * ldb * 2 + csrc;
  const char* gB1 = (const char*)Bt + (size_t)(n0 + 64 + sr) * ldb * 2 + csrc;
  char* lA0 = As + t * 16;
  char* lA1 = As + 4096 + t * 16;
  char* lB0 = Bs + t * 16;
  char* lB1 = Bs + 4096 + t * 16;

  int aoff[4], boff[4];
#pragma unroll
  for (int mi = 0; mi < 4; ++mi) {
    int r = wr * 64 + mi * 16 + (lane & 15);
    aoff[mi] = r * 64 + ((((lane >> 4)) ^ ((r >> 1) & 3)) << 4);
  }
#pragma unroll
  for (int ni = 0; ni < 4; ++ni) {
    int r = wc * 64 + ni * 16 + (lane & 15);
    boff[ni] = r * 64 + ((((lane >> 4)) ^ ((r >> 1) & 3)) << 4);
  }

  for (int k0 = 0; k0 < K; k0 += 32) {
    const size_t kb = (size_t)k0 * 2;
    __syncthreads();
    GLDS16(gA0 + kb, lA0);
    GLDS16(gA1 + kb, lA1);
    GLDS16(gB0 + kb, lB0);
    GLDS16(gB1 + kb, lB1);
    __syncthreads();
    bf16x8 av[4], bv[4];
#pragma unroll
    for (int mi = 0; mi < 4; ++mi) av[mi] = *(const bf16x8*)(As + aoff[mi]);
#pragma unroll
    for (int ni = 0; ni < 4; ++ni) bv[ni] = *(const bf16x8*)(Bs + boff[ni]);
#pragma unroll
    for (int mi = 0; mi < 4; ++mi)
#pragma unroll
      for (int ni = 0; ni < 4; ++ni)
        acc[mi][ni] = __builtin_amdgcn_mfma_f32_16x16x32_bf16(av[mi], bv[ni], acc[mi][ni], 0, 0, 0);
  }
}

// --- GAT dst-side transform: C = relu(y @ Wt + biases), bf16 out, N=128 ---
struct GJob { const bf16_t* A; const bf16_t* Bt; bf16_t* C; int M; int K;
              const float *b1, *b2, *b3; };
struct Gemm3 { GJob j[3]; };
__global__ __launch_bounds__(256) void k_gemm_g3(Gemm3 g) {
  const GJob& jb = g.j[blockIdx.y];
  int m0 = blockIdx.x * 128;
  if (m0 >= jb.M) return;
  f32x4 acc[4][4];
  mfma_core(jb.A, jb.Bt, jb.M, jb.K, jb.K, m0, 0, acc);
  const int t = threadIdx.x, lane = t & 63, wid = t >> 6;
  const int wr = wid >> 1, wc = wid & 1;
  const int col0 = lane & 15, rsub = (lane >> 4) * 4;
#pragma unroll
  for (int mi = 0; mi < 4; ++mi) {
#pragma unroll
    for (int ni = 0; ni < 4; ++ni) {
      int c = wc * 64 + ni * 16 + col0;
      float bb = jb.b1[c];
      if (jb.b2) bb += jb.b2[c];
      if (jb.b3) bb += jb.b3[c];
#pragma unroll
      for (int rg = 0; rg < 4; ++rg) {
        int r = m0 + wr * 64 + mi * 16 + rsub + rg;
        if (r < jb.M) jb.C[(size_t)r * H + c] = (bf16_t)fmaxf(acc[mi][ni][rg] + bb, 0.f);
      }
    }
  }
}

// --- head slice GEMMs: P = (x @ W1slice) * rowscale + b1/3, bf16 out ---
struct PJob { const bf16_t* A; bf16_t* C; int M; const float* rs; };
struct GemmPS { PJob j[3]; const bf16_t* Bt; const float* b1t; };
__global__ __launch_bounds__(256) void k_gemm_ps(GemmPS g) {
  const PJob& jb = g.j[blockIdx.y];
  int mt = blockIdx.x / 6, nt = blockIdx.x - mt * 6;
  int m0 = mt * 128;
  if (m0 >= jb.M) return;
  int n0 = nt * 128;
  f32x4 acc[4][4];
  mfma_core(jb.A, g.Bt + blockIdx.y * 128, jb.M, 128, 384, m0, n0, acc);
  const int t = threadIdx.x, lane = t & 63, wid = t >> 6;
  const int wr = wid >> 1, wc = wid & 1;
  const int col0 = lane & 15, rsub = (lane >> 4) * 4;
#pragma unroll
  for (int mi = 0; mi < 4; ++mi) {
#pragma unroll
    for (int rg = 0; rg < 4; ++rg) {
      int r = m0 + wr * 64 + mi * 16 + rsub + rg;
      if (r < jb.M) {
        float sc = jb.rs[r];
#pragma unroll
        for (int ni = 0; ni < 4; ++ni) {
          int c = n0 + wc * 64 + ni * 16 + col0;
          jb.C[(size_t)r * 768 + c] = (bf16_t)(acc[mi][ni][rg] * sc + g.b1t[c]);
        }
      }
    }
  }
}

// --- fused head, BM=64 x BN=256 single pass: A-tile = relu(Pa[d1]+Pb[d2]+Pc[ce])
//     built in-kernel from bf16 tables; GEMM vs all 256 cols of W2t; epilogue
//     fuses relu + W3 -> atomicAdd into out. 469 blocks -> ~2 blocks/CU. ---
__global__ __launch_bounds__(256) void k_w2head(
    const bf16_t* __restrict__ Pa, const bf16_t* __restrict__ Pb, const bf16_t* __restrict__ Pc,
    const int* __restrict__ d1, const int* __restrict__ d2, const int* __restrict__ ce,
    const bf16_t* __restrict__ W2t, const float* __restrict__ b2,
    const float* __restrict__ W3, const float* __restrict__ b3,
    float* __restrict__ out, int cn)
{
  __shared__ char As[64 * 64];
  __shared__ char Bs[256 * 64];
  const int t = threadIdx.x;
  const int lane = t & 63;
  const int m0 = blockIdx.x * 64;
  if (m0 >= cn) return;
  f32x4 acc[2][8];
#pragma unroll
  for (int mi = 0; mi < 2; ++mi)
#pragma unroll
    for (int ni = 0; ni < 8; ++ni) acc[mi][ni] = (f32x4){0.f, 0.f, 0.f, 0.f};

  // A gather role: row = t>>2 (0..63), 16B chunk ac = t&3 (8 bf16)
  const int arow = t >> 2;
  const int ac = t & 3;
  int gr = m0 + arow; if (gr >= cn) gr = cn - 1;
  const bf16_t* pa = Pa + (size_t)d1[gr] * 768 + ac * 8;
  const bf16_t* pb = Pb + (size_t)d2[gr] * 768 + ac * 8;
  const bf16_t* pc = Pc + (size_t)ce[gr] * 768 + ac * 8;
  char* la = As + arow * 64 + ((ac ^ ((arow >> 1) & 3)) << 4);

  // B staging: 256 rows x 32k in 4 quarters (global_load_lds)
  const int sr = t >> 2;
  const int sc = t & 3;
  const int csrc = ((sc ^ ((sr >> 1) & 3)) << 4);
  const char* gB = (const char*)W2t + (size_t)sr * 768 * 2 + csrc;
  const size_t qstep = (size_t)64 * 768 * 2;

  const int wid = t >> 6;
  const int wr = wid >> 1, wc = wid & 1;
  int aoff[2], boff[8];
#pragma unroll
  for (int mi = 0; mi < 2; ++mi) {
    int r = wr * 32 + mi * 16 + (lane & 15);
    aoff[mi] = r * 64 + ((((lane >> 4)) ^ ((r >> 1) & 3)) << 4);
  }
#pragma unroll
  for (int ni = 0; ni < 8; ++ni) {
    int r = wc * 128 + ni * 16 + (lane & 15);
    boff[ni] = r * 64 + ((((lane >> 4)) ^ ((r >> 1) & 3)) << 4);
  }

  for (int k0 = 0; k0 < 768; k0 += 32) {
    uint4 Ua = *(const uint4*)(pa + k0);
    uint4 Ub = *(const uint4*)(pb + k0);
    uint4 Uc = *(const uint4*)(pc + k0);
    float s0 = bflo(Ua.x) + bflo(Ub.x) + bflo(Uc.x);
    float s1 = bfhi(Ua.x) + bfhi(Ub.x) + bfhi(Uc.x);
    float s2 = bflo(Ua.y) + bflo(Ub.y) + bflo(Uc.y);
    float s3 = bfhi(Ua.y) + bfhi(Ub.y) + bfhi(Uc.y);
    float s4 = bflo(Ua.z) + bflo(Ub.z) + bflo(Uc.z);
    float s5 = bfhi(Ua.z) + bfhi(Ub.z) + bfhi(Uc.z);
    float s6 = bflo(Ua.w) + bflo(Ub.w) + bflo(Uc.w);
    float s7 = bfhi(Ua.w) + bfhi(Ub.w) + bfhi(Uc.w);
    uint4 P;
    P.x = packbf(fmaxf(s0, 0.f), fmaxf(s1, 0.f));
    P.y = packbf(fmaxf(s2, 0.f), fmaxf(s3, 0.f));
    P.z = packbf(fmaxf(s4, 0.f), fmaxf(s5, 0.f));
    P.w = packbf(fmaxf(s6, 0.f), fmaxf(s7, 0.f));
    const size_t kb = (size_t)k0 * 2;
    __syncthreads();
    GLDS16(gB + kb,             Bs + t * 16);
    GLDS16(gB + qstep + kb,     Bs + 4096 + t * 16);
    GLDS16(gB + 2 * qstep + kb, Bs + 8192 + t * 16);
    GLDS16(gB + 3 * qstep + kb, Bs + 12288 + t * 16);
    *(uint4*)la = P;
    __syncthreads();
    bf16x8 av[2], bv[8];
#pragma unroll
    for (int mi = 0; mi < 2; ++mi) av[mi] = *(const bf16x8*)(As + aoff[mi]);
#pragma unroll
    for (int ni = 0; ni < 8; ++ni) bv[ni] = *(const bf16x8*)(Bs + boff[ni]);
#pragma unroll
    for (int mi = 0; mi < 2; ++mi)
#pragma unroll
      for (int ni = 0; ni < 8; ++ni)
        acc[mi][ni] = __builtin_amdgcn_mfma_f32_16x16x32_bf16(av[mi], bv[ni], acc[mi][ni], 0, 0, 0);
  }

  const int col0 = lane & 15, rsub = (lane >> 4) * 4;
  float w0[8], w1[8], bb[8];
#pragma unroll
  for (int ni = 0; ni < 8; ++ni) {
    int c = wc * 128 + ni * 16 + col0;
    w0[ni] = W3[2 * c]; w1[ni] = W3[2 * c + 1]; bb[ni] = b2[c];
  }
#pragma unroll
  for (int mi = 0; mi < 2; ++mi) {
#pragma unroll
    for (int rg = 0; rg < 4; ++rg) {
      int r = m0 + wr * 32 + mi * 16 + rsub + rg;
      float p0 = 0.f, p1 = 0.f;
#pragma unroll
      for (int ni = 0; ni < 8; ++ni) {
        float v = fmaxf(acc[mi][ni][rg] + bb[ni], 0.f);
        p0 = fmaf(v, w0[ni], p0);
        p1 = fmaf(v, w1[ni], p1);
      }
#pragma unroll
      for (int off = 1; off < 16; off <<= 1) {
        p0 += __shfl_xor(p0, off);
        p1 += __shfl_xor(p1, off);
      }
      if (col0 == 0 && r < cn) {
        if (wc == 0) { p0 += b3[0]; p1 += b3[1]; }
        atomicAdd(&out[(size_t)r * 2], p0);
        atomicAdd(&out[(size_t)r * 2 + 1], p1);
      }
    }
  }
}

// ================= conversions (emb->bf16 + b1/3 fused) =================
__global__ __launch_bounds__(256) void k_conv_emb(
    const float* __restrict__ xd, const float* __restrict__ xp, const float* __restrict__ xc,
    bf16_t* __restrict__ od, bf16_t* __restrict__ op, bf16_t* __restrict__ oc,
    const float* __restrict__ b1, float* __restrict__ b1t)
{
  int i = blockIdx.x * 256 + threadIdx.x;
  const int SD = ND * H, SP = NPN * H, SC = NCN * H;
  if (i < SD) od[i] = (bf16_t)xd[i];
  else if (i < SD + SP) op[i - SD] = (bf16_t)xp[i - SD];
  else if (i < SD + SP + SC) oc[i - SD - SP] = (bf16_t)xc[i - SD - SP];
  else if (i < SD + SP + SC + 768) { int j = i - SD - SP - SC; b1t[j] = b1[j] * (1.f / 3.f); }
}

// LDS-tiled transpose-convert: dst[n*Kfull+koff+k] = bf16(src[k*N+n])
struct TC { const float* src[12]; bf16_t* dst[12]; int Ksub[12]; int N[12]; int Kfull[12]; int koff[12]; };
__global__ __launch_bounds__(256) void k_tconv2(TC a) {
  int m = blockIdx.z;
  int Ks = a.Ksub[m], N = a.N[m];
  int tx = blockIdx.x * 32;
  int ty = blockIdx.y * 32;
  if (tx >= N || ty >= Ks) return;
  __shared__ float tile[32][33];
  int c = threadIdx.x & 31, rr = threadIdx.x >> 5;
#pragma unroll
  for (int kk = rr; kk < 32; kk += 8)
    if (ty + kk < Ks && tx + c < N) tile[kk][c] = a.src[m][(size_t)(ty + kk) * N + tx + c];
  __syncthreads();
  bf16_t* dst = a.dst[m];
  int Kf = a.Kfull[m], ko = a.koff[m];
#pragma unroll
  for (int nn = rr; nn < 32; nn += 8)
    if (tx + nn < N && ty + c < Ks)
      dst[(size_t)(tx + nn) * Kf + ko + ty + c] = (bf16_t)tile[c][nn];
}

// ---------------- wv = W @ a : both layers, 20 matvecs ----------------
struct Wd20 { const float* W[20]; const float* a[20]; float* o[20]; };
__global__ __launch_bounds__(128) void k_wd20(Wd20 g) {
  int m = blockIdx.x;
  int k = threadIdx.x;
  const float* Wp = g.W[m];
  const float* av = g.a[m];
  float s = 0.f;
#pragma unroll 4
  for (int j = 0; j < H; ++j) s = fmaf(Wp[k * H + j], av[j], s);
  g.o[m][k] = s;
}

// ---------------- fused node scores ----------------
struct Sc { const bf16_t* xd; const bf16_t* xp; const bf16_t* xc; const float* wv;
            float* ss[5]; float* sd[5]; };
__global__ __launch_bounds__(256) void k_scores(Sc S) {
  int row = blockIdx.x * 4 + (threadIdx.x >> 6);
  if (row >= ND + NPN + NCN) return;
  int lane = threadIdx.x & 63;
  const bf16_t* x;
  int idx, cls;
  if (row < ND) { x = S.xd; idx = row; cls = 0; }
  else if (row < ND + NPN) { x = S.xp; idx = row - ND; cls = 1; }
  else { x = S.xc; idx = row - ND - NPN; cls = 2; }
  unsigned u = *(const unsigned*)(x + (size_t)idx * H + lane * 2);
  float x0 = bflo(u), x1 = bfhi(u);
  const float* wv = S.wv;
#define DOT(vi, outp) { const float* v = wv + (vi) * H; \
    float s = x0 * v[2 * lane] + x1 * v[2 * lane + 1]; s = wred_sum(s); \
    if (!lane) (outp)[idx] = s; }
  if (cls == 0) {
    DOT(0, S.ss[0]); DOT(8, S.sd[3]);
  } else if (cls == 1) {
    DOT(1, S.ss[1]); DOT(3, S.ss[3]); DOT(4, S.ss[4]);
    DOT(5, S.sd[0]); DOT(6, S.sd[1]); DOT(7, S.sd[2]);
  } else {
    DOT(2, S.ss[2]); DOT(9, S.sd[4]);
  }
#undef DOT
}

// ---------------- CSR build (u16 payload, 4-edge ILP) ----------------
struct CsrArgs {
  const int* src[5]; const int* dst[5];
  int E[5]; int n[5];
  int* cnt[5]; int* cur[5]; int* starts[5]; u16* csr[5];
};
__global__ __launch_bounds__(256) void k_count5(CsrArgs a) {
  int rel = blockIdx.y;
  int E = a.E[rel];
  const int* dst = a.dst[rel];
  int* cnt = a.cnt[rel];
  int e0 = blockIdx.x * 1024 + threadIdx.x;
#pragma unroll
  for (int u = 0; u < 4; ++u) {
    int e = e0 + u * 256;
    if (e < E) atomicAdd(&cnt[dst[e]], 1);
  }
}
__global__ __launch_bounds__(1024) void k_scan5(CsrArgs a) {
  int rel = blockIdx.x;
  int n = a.n[rel];
  const int* cnt = a.cnt[rel];
  int* st = a.starts[rel];
  int* cu = a.cur[rel];
  int t = threadIdx.x;
  int stripe = (n + 1023) / 1024;
  int lo = t * stripe;
  int hi = lo + stripe; if (hi > n) hi = n;
  int s = 0;
  for (int i = lo; i < hi; ++i) s += cnt[i];
  int lane = t & 63, wv = t >> 6;
  int x = s;
#pragma unroll
  for (int off = 1; off < 64; off <<= 1) {
    int y = __shfl_up(x, off);
    if (lane >= off) x += y;
  }
  __shared__ int ws[16];
  if (lane == 63) ws[wv] = x;
  __syncthreads();
  if (t == 0) {
    int run = 0;
#pragma unroll
    for (int i = 0; i < 16; ++i) { int v = ws[i]; ws[i] = run; run += v; }
  }
  __syncthreads();
  int run = ws[wv] + x - s;
  for (int i = lo; i < hi; ++i) { st[i] = run; cu[i] = run; run += cnt[i]; }
  if (t == 1023) st[n] = ws[15] + x;
}
__global__ __launch_bounds__(256) void k_fill5(CsrArgs a) {
  int rel = blockIdx.y;
  int E = a.E[rel];
  const int* dst = a.dst[rel];
  const int* src = a.src[rel];
  int* cur = a.cur[rel];
  u16* csr = a.csr[rel];
  int e0 = blockIdx.x * 1024 + threadIdx.x;
#pragma unroll
  for (int u = 0; u < 4; ++u) {
    int e = e0 + u * 256;
    if (e < E) {
      int pos = atomicAdd(&cur[dst[e]], 1);
      csr[pos] = (u16)src[e];
    }
  }
}

// ---------------- GAT aggregate on RAW x; analytic pp self-loop ----------------
struct Agg5 {
  const u16* csr[5]; const int* starts[5];
  const float* ss[5]; const float* sd[5];
  const bf16_t* xs[5];
  bf16_t* y[5]; int ystride[5]; int ycoff[5]; int ndst[5]; int self[5];
};
__global__ __launch_bounds__(256) void k_agg5(Agg5 a) {
  int rel = blockIdx.y;
  int d = blockIdx.x * 4 + (threadIdx.x >> 6);
  if (d >= a.ndst[rel]) return;
  int lane = threadIdx.x & 63;
  int g = lane >> 4, j16 = lane & 15;
  bf16_t* yrow = a.y[rel] + (size_t)d * a.ystride[rel] + a.ycoff[rel];
  int s0 = a.starts[rel][d];
  int deg = a.starts[rel][d + 1] - s0;
  int selfa = a.self[rel];
  if (!deg && !selfa) {
    if (g == 0) *(uint4*)(yrow + j16 * 8) = make_uint4(0u, 0u, 0u, 0u);
    return;
  }
  const u16* cs = a.csr[rel] + s0;
  const float* ssp = a.ss[rel];
  const bf16_t* xsp = a.xs[rel];
  float sdv = a.sd[rel][d];
  float acc[8] = {0.f, 0.f, 0.f, 0.f, 0.f, 0.f, 0.f, 0.f};
  float ps = 0.f;
  for (int b = 0; b < deg; b += 16) {
#pragma unroll
    for (int u = 0; u < 4; ++u) {
      int i = b + u * 4 + g;
      float p = 0.f;
      uint4 U = make_uint4(0u, 0u, 0u, 0u);
      if (i < deg) {
        int s = cs[i];
        float e = ssp[s] + sdv; e = e > 0.f ? e : 0.2f * e;
        p = __expf(e);
        U = *(const uint4*)(xsp + (size_t)s * H + j16 * 8);
      }
      ps += p;
      acc[0] = fmaf(p, bflo(U.x), acc[0]); acc[1] = fmaf(p, bfhi(U.x), acc[1]);
      acc[2] = fmaf(p, bflo(U.y), acc[2]); acc[3] = fmaf(p, bfhi(U.y), acc[3]);
      acc[4] = fmaf(p, bflo(U.z), acc[4]); acc[5] = fmaf(p, bfhi(U.z), acc[5]);
      acc[6] = fmaf(p, bflo(U.w), acc[6]); acc[7] = fmaf(p, bfhi(U.w), acc[7]);
    }
  }
  if (selfa && g == 0) {
    float e = ssp[d] + sdv; e = e > 0.f ? e : 0.2f * e;
    float p = __expf(e);
    uint4 U = *(const uint4*)(xsp + (size_t)d * H + j16 * 8);
    ps += p;
    acc[0] = fmaf(p, bflo(U.x), acc[0]); acc[1] = fmaf(p, bfhi(U.x), acc[1]);
    acc[2] = fmaf(p, bflo(U.y), acc[2]); acc[3] = fmaf(p, bfhi(U.y), acc[3]);
    acc[4] = fmaf(p, bflo(U.z), acc[4]); acc[5] = fmaf(p, bfhi(U.z), acc[5]);
    acc[6] = fmaf(p, bflo(U.w), acc[6]); acc[7] = fmaf(p, bfhi(U.w), acc[7]);
  }
#pragma unroll
  for (int e = 0; e < 8; ++e) {
    acc[e] += __shfl_xor(acc[e], 16);
    acc[e] += __shfl_xor(acc[e], 32);
  }
  ps += __shfl_xor(ps, 16);
  ps += __shfl_xor(ps, 32);
  if (g == 0) {
    float inv = 1.f / ps;
    uint4 O;
    O.x = packbf(acc[0] * inv, acc[1] * inv);
    O.y = packbf(acc[2] * inv, acc[3] * inv);
    O.z = packbf(acc[4] * inv, acc[5] * inv);
    O.w = packbf(acc[6] * inv, acc[7] * inv);
    *(uint4*)(yrow + j16 * 8) = O;
  }
}

// ---------------- readout ----------------
__global__ __launch_bounds__(256) void k_invnorm(
    const bf16_t* __restrict__ xd, const bf16_t* __restrict__ xc,
    float* __restrict__ invd, float* __restrict__ invc)
{
  int row = blockIdx.x * 4 + (threadIdx.x >> 6);
  if (row >= ND + NCN) return;
  int lane = threadIdx.x & 63;
  const bf16_t* x = (row < ND) ? xd + (size_t)row * H : xc + (size_t)(row - ND) * H;
  unsigned u = ((const unsigned*)x)[lane];
  float av = bflo(u), bv = bfhi(u);
  float s = wred_sum(av * av + bv * bv);
  if (!lane) {
    float nv = fmaxf(sqrtf(s), 1e-12f);
    if (row < ND) invd[row] = 1.f / nv; else invc[row - ND] = 1.f / nv;
  }
}

// ================= host =================
extern "C" void kernel_launch(void* const* d_in, const int* in_sizes, int n_in,
                              void* d_out, int out_size, void* d_ws, size_t ws_size,
                              hipStream_t stream)
{
  (void)in_sizes; (void)n_in;
  const float* drug_emb    = (const float*)d_in[0];
  const float* protein_emb = (const float*)d_in[1];
  const float* cell_emb    = (const float*)d_in[2];
  // internal rel order: 0=dp, 1=pp, 2=cp, 3=rdp, 4=rcp
  const int base_idx[5] = {3, 11, 15, 7, 19};
  const float *W_[5], *as_[5], *ad_[5], *b_[5];
  for (int r = 0; r < 5; ++r) {
    W_[r]  = (const float*)d_in[base_idx[r]];
    as_[r] = (const float*)d_in[base_idx[r] + 1];
    ad_[r] = (const float*)d_in[base_idx[r] + 2];
    b_[r]  = (const float*)d_in[base_idx[r] + 3];
  }
  const float* W1 = (const float*)d_in[23]; const float* b1 = (const float*)d_in[24];
  const float* W2 = (const float*)d_in[25]; const float* b2 = (const float*)d_in[26];
  const float* W3 = (const float*)d_in[27]; const float* b3 = (const float*)d_in[28];
  const int* src_dp = (const int*)d_in[29]; const int* dst_dp = (const int*)d_in[30];
  const int* src_pp = (const int*)d_in[31]; const int* dst_pp = (const int*)d_in[32];
  const int* src_cp = (const int*)d_in[33]; const int* dst_cp = (const int*)d_in[34];
  const int* drug1  = (const int*)d_in[35]; const int* drug2  = (const int*)d_in[36];
  const int* cellb  = (const int*)d_in[37];
  float* out = (float*)d_out;

  char* wsb = (char*)d_ws;
  size_t off = 0;
  auto alloc = [&](size_t bytes) -> void* {
    void* p = wsb + off;
    off += (bytes + 255) & ~(size_t)255;
    return p;
  };
  bf16_t* xdb[2] = {(bf16_t*)alloc((size_t)ND * H * 2),  (bf16_t*)alloc((size_t)ND * H * 2)};
  bf16_t* xpb[2] = {(bf16_t*)alloc((size_t)NPN * H * 2), (bf16_t*)alloc((size_t)NPN * H * 2)};
  bf16_t* xcb[2] = {(bf16_t*)alloc((size_t)NCN * H * 2), (bf16_t*)alloc((size_t)NCN * H * 2)};
  const int Msrc[5] = {ND, NPN, NCN, NPN, NPN};
  const int Mdst[5] = {NPN, NPN, NPN, ND, NCN};
  const int Erel[5] = {E_DP, E_PP, E_CP, E_DP, E_CP};
  bf16_t* yp = (bf16_t*)alloc((size_t)NPN * 384 * 2);
  bf16_t* yd = (bf16_t*)alloc((size_t)ND * H * 2);
  bf16_t* yc = (bf16_t*)alloc((size_t)NCN * H * 2);
  bf16_t* Wtp = (bf16_t*)alloc((size_t)NLAYERS * 128 * 384 * 2);
  bf16_t* Wtd = (bf16_t*)alloc((size_t)NLAYERS * 128 * 128 * 2);
  bf16_t* Wtc = (bf16_t*)alloc((size_t)NLAYERS * 128 * 128 * 2);
  bf16_t* W1t = (bf16_t*)alloc((size_t)768 * 384 * 2);
  bf16_t* W2t = (bf16_t*)alloc((size_t)256 * 768 * 2);
  float* wvb = (float*)alloc(20 * H * 4);
  float* b1t = (float*)alloc(768 * 4);
  float* ssb[5]; for (int r = 0; r < 5; ++r) ssb[r] = (float*)alloc((size_t)Msrc[r] * 4);
  float* sdb[5]; for (int r = 0; r < 5; ++r) sdb[r] = (float*)alloc((size_t)Mdst[r] * 4);
  int* cnt_all = (int*)alloc(62000 * 4);
  int* cur_all = (int*)alloc(62000 * 4);
  int* st_all  = (int*)alloc((62000 + 5) * 4);
  int *cntb[5], *curb[5], *stb[5];
  { int o = 0, o2 = 0;
    for (int r = 0; r < 5; ++r) {
      cntb[r] = cnt_all + o; curb[r] = cur_all + o; stb[r] = st_all + o2;
      o += Mdst[r]; o2 += Mdst[r] + 1;
    } }
  u16* csrb[5]; for (int r = 0; r < 5; ++r) csrb[r] = (u16*)alloc((size_t)Erel[r] * 2);
  float* invd = (float*)alloc(ND * 4);
  float* invc = (float*)alloc(NCN * 4);
  bf16_t* P1a = (bf16_t*)alloc((size_t)ND * 768 * 2);
  bf16_t* P1b = (bf16_t*)alloc((size_t)ND * 768 * 2);
  bf16_t* P1c = (bf16_t*)alloc((size_t)NCN * 768 * 2);
  (void)ws_size;

  // zero the output (fused head accumulates into it)
  hipMemsetAsync(out, 0, (size_t)out_size * 4, stream);

  // conversions (+ b1/3)
  k_conv_emb<<<(ND * H + NPN * H + NCN * H + 768 + 255) / 256, 256, 0, stream>>>(
      drug_emb, protein_emb, cell_emb, xdb[0], xpb[0], xcb[0], b1, b1t);
  TC tc;
  for (int l = 0; l < 2; ++l) {
    for (int r = 0; r < 3; ++r) {
      int m = l * 3 + r;
      tc.src[m] = W_[r] + (size_t)l * H * H;
      tc.dst[m] = Wtp + (size_t)l * 128 * 384;
      tc.Ksub[m] = 128; tc.N[m] = 128; tc.Kfull[m] = 384; tc.koff[m] = r * 128;
    }
    tc.src[6 + l] = W_[3] + (size_t)l * H * H; tc.dst[6 + l] = Wtd + (size_t)l * 128 * 128;
    tc.Ksub[6 + l] = 128; tc.N[6 + l] = 128; tc.Kfull[6 + l] = 128; tc.koff[6 + l] = 0;
    tc.src[8 + l] = W_[4] + (size_t)l * H * H; tc.dst[8 + l] = Wtc + (size_t)l * 128 * 128;
    tc.Ksub[8 + l] = 128; tc.N[8 + l] = 128; tc.Kfull[8 + l] = 128; tc.koff[8 + l] = 0;
  }
  tc.src[10] = W1; tc.dst[10] = W1t; tc.Ksub[10] = 384; tc.N[10] = 768; tc.Kfull[10] = 384; tc.koff[10] = 0;
  tc.src[11] = W2; tc.dst[11] = W2t; tc.Ksub[11] = 768; tc.N[11] = 256; tc.Kfull[11] = 768; tc.koff[11] = 0;
  k_tconv2<<<dim3(24, 24, 12), 256, 0, stream>>>(tc);

  // wv for both layers
  Wd20 wg;
  for (int l = 0; l < 2; ++l)
    for (int r = 0; r < 5; ++r) {
      int m = l * 10 + r;
      wg.W[m] = W_[r] + (size_t)l * H * H; wg.a[m] = as_[r] + l * H; wg.o[m] = wvb + m * H;
      int m2 = l * 10 + 5 + r;
      wg.W[m2] = W_[r] + (size_t)l * H * H; wg.a[m2] = ad_[r] + l * H; wg.o[m2] = wvb + m2 * H;
    }
  k_wd20<<<20, 128, 0, stream>>>(wg);

  // CSR build (u16; pp WITHOUT self-loops — handled analytically in agg)
  hipMemsetAsync(cnt_all, 0, 62000 * 4, stream);
  CsrArgs ca;
  const int* srcA[5] = {src_dp, src_pp, src_cp, dst_dp, dst_cp};
  const int* dstA[5] = {dst_dp, dst_pp, dst_cp, src_dp, src_cp};
  for (int r = 0; r < 5; ++r) {
    ca.src[r] = srcA[r]; ca.dst[r] = dstA[r]; ca.E[r] = Erel[r]; ca.n[r] = Mdst[r];
    ca.cnt[r] = cntb[r]; ca.cur[r] = curb[r]; ca.starts[r] = stb[r]; ca.csr[r] = csrb[r];
  }
  dim3 egrid((E_PP + 1023) / 1024, 5);
  k_count5<<<egrid, 256, 0, stream>>>(ca);
  k_scan5<<<5, 1024, 0, stream>>>(ca);
  k_fill5<<<egrid, 256, 0, stream>>>(ca);

  int cur = 0;
  for (int l = 0; l < NLAYERS; ++l) {
    int nxt = 1 - cur;
    const bf16_t* xsrc[5] = {xdb[cur], xpb[cur], xcb[cur], xpb[cur], xpb[cur]};
    Sc sc;
    sc.xd = xdb[cur]; sc.xp = xpb[cur]; sc.xc = xcb[cur]; sc.wv = wvb + l * 10 * H;
    for (int r = 0; r < 5; ++r) { sc.ss[r] = ssb[r]; sc.sd[r] = sdb[r]; }
    k_scores<<<(ND + NPN + NCN + 3) / 4, 256, 0, stream>>>(sc);
    Agg5 aa;
    bf16_t* yptr[5] = {yp, yp, yp, yd, yc};
    const int ystr[5] = {384, 384, 384, 128, 128};
    const int ycof[5] = {0, 128, 256, 0, 0};
    const int selfs[5] = {0, 1, 0, 0, 0};
    for (int r = 0; r < 5; ++r) {
      aa.csr[r] = csrb[r]; aa.starts[r] = stb[r]; aa.ss[r] = ssb[r]; aa.sd[r] = sdb[r];
      aa.xs[r] = xsrc[r]; aa.y[r] = yptr[r]; aa.ystride[r] = ystr[r]; aa.ycoff[r] = ycof[r];
      aa.ndst[r] = Mdst[r]; aa.self[r] = selfs[r];
    }
    k_agg5<<<dim3((NPN + 3) / 4, 5), 256, 0, stream>>>(aa);
    Gemm3 g3;
    g3.j[0] = {yp, Wtp + (size_t)l * 128 * 384, xpb[nxt], NPN, 384,
               b_[0] + l * H, b_[1] + l * H, b_[2] + l * H};
    g3.j[1] = {yd, Wtd + (size_t)l * 128 * 128, xdb[nxt], ND, 128,
               b_[3] + l * H, nullptr, nullptr};
    g3.j[2] = {yc, Wtc + (size_t)l * 128 * 128, xcb[nxt], NCN, 128,
               b_[4] + l * H, nullptr, nullptr};
    k_gemm_g3<<<dim3((NPN + 127) / 128, 3), 256, 0, stream>>>(g3);
    cur = nxt;
  }

  // head: inv-norms -> scaled slice GEMMs (bf16 P tables, b1/3 baked) -> fused gather+W2+W3
  k_invnorm<<<(ND + NCN + 3) / 4, 256, 0, stream>>>(xdb[cur], xcb[cur], invd, invc);
  GemmPS ps;
  ps.Bt = W1t; ps.b1t = b1t;
  ps.j[0] = {xdb[cur], P1a, ND, invd};
  ps.j[1] = {xdb[cur], P1b, ND, invd};
  ps.j[2] = {xcb[cur], P1c, NCN, invc};
  k_gemm_ps<<<dim3(32 * 6, 3), 256, 0, stream>>>(ps);
  k_w2head<<<(NB + 63) / 64, 256, 0, stream>>>(
      P1a, P1b, P1c, drug1, drug2, cellb, W2t, b2, W3, b3, out, NB);
}